// Round 13
// baseline (969.160 us; speedup 1.0000x reference)
//
#include <hip/hip_runtime.h>

#define VN 30000
#define CN 120000
#define EPN 180000
#define ENN 180000
#define DD 128
#define BN 32
#define SCN (2*VN + 2*CN)          // 300000 concatenated degree rows: PV | NV | PC | NC
#define SC_NB ((SCN + 1023) / 1024) // 293 scan blocks

using bf16x8 = __attribute__((ext_vector_type(8))) short;
using f32x4  = __attribute__((ext_vector_type(4))) float;

static __device__ __forceinline__ float sigm(float x){ return 1.0f/(1.0f+__expf(-x)); }
static __device__ __forceinline__ unsigned short f2b(float f){
  unsigned int u = __float_as_uint(f);
  unsigned int r = u + 0x7fffu + ((u>>16)&1u);
  return (unsigned short)(r>>16);
}
static __device__ __forceinline__ float b2f(unsigned short s){
  return __uint_as_float(((unsigned int)s)<<16);
}

// ---------------- edge endpoints + integer degree counts ----------------
__global__ __launch_bounds__(256) void k_edges(
    const int* __restrict__ vE, const int* __restrict__ cE,
    const int* __restrict__ pE, const int* __restrict__ nE,
    int* __restrict__ p_v, int* __restrict__ p_c,
    int* __restrict__ n_v, int* __restrict__ n_c,
    int* __restrict__ cnt)
{
  int i = blockIdx.x*256 + threadIdx.x;
  if (i < EPN){
    int e = pE[i]; int v = vE[e], c = cE[e];
    p_v[i] = v; p_c[i] = c;
    atomicAdd(&cnt[v], 1); atomicAdd(&cnt[2*VN + c], 1);
  }
  if (i < ENN){
    int e = nE[i]; int v = vE[e], c = cE[e];
    n_v[i] = v; n_c[i] = c;
    atomicAdd(&cnt[VN + v], 1); atomicAdd(&cnt[2*VN + CN + c], 1);
  }
}

// ---------------- 3-phase exclusive scan over cnt[SCN] ----------------
__global__ __launch_bounds__(256) void k_scan1(const int* __restrict__ cnt, int* __restrict__ part, int* __restrict__ bsum){
  __shared__ int s[256];
  int b = blockIdx.x, t = threadIdx.x;
  int base = b*1024 + t*4;
  int v0 = (base+0<SCN)?cnt[base+0]:0;
  int v1 = (base+1<SCN)?cnt[base+1]:0;
  int v2 = (base+2<SCN)?cnt[base+2]:0;
  int v3 = (base+3<SCN)?cnt[base+3]:0;
  int loc = v0+v1+v2+v3;
  s[t] = loc; __syncthreads();
  for (int off=1; off<256; off<<=1){
    int x = (t>=off)? s[t-off] : 0;
    __syncthreads();
    s[t] += x;
    __syncthreads();
  }
  int excl = s[t]-loc;
  if (t==255) bsum[b] = s[255];
  if (base  <SCN) part[base  ] = excl;
  if (base+1<SCN) part[base+1] = excl+v0;
  if (base+2<SCN) part[base+2] = excl+v0+v1;
  if (base+3<SCN) part[base+3] = excl+v0+v1+v2;
}
__global__ __launch_bounds__(512) void k_scan2(const int* __restrict__ bsum, int* __restrict__ boff, int* __restrict__ total_out){
  __shared__ int s[512];
  int t = threadIdx.x;
  int v = (t<SC_NB)? bsum[t] : 0;
  s[t]=v; __syncthreads();
  for (int off=1; off<512; off<<=1){
    int x = (t>=off)? s[t-off] : 0;
    __syncthreads();
    s[t]+=x;
    __syncthreads();
  }
  if (t<SC_NB) boff[t] = s[t]-v;
  if (t==511) total_out[0] = s[511];
}
__global__ __launch_bounds__(256) void k_scan3(int* __restrict__ part, const int* __restrict__ boff){
  int b = blockIdx.x; int base = b*1024 + threadIdx.x*4; int o = boff[b];
  #pragma unroll
  for (int i=0;i<4;i++) if (base+i < SCN) part[base+i] += o;
}

// ---------------- CSR bucket fill ----------------
__global__ __launch_bounds__(256) void k_fill(
    const int* __restrict__ p_v, const int* __restrict__ p_c,
    const int* __restrict__ n_v, const int* __restrict__ n_c,
    const int* __restrict__ starts, int* __restrict__ fill, int* __restrict__ listBuf)
{
  int i = blockIdx.x*256 + threadIdx.x;
  if (i < EPN){
    int v = p_v[i], c = p_c[i];
    int s1 = starts[v]        + atomicAdd(&fill[v], 1);          listBuf[s1] = c; // PV
    int s2 = starts[2*VN + c] + atomicAdd(&fill[2*VN + c], 1);   listBuf[s2] = v; // PC
  }
  if (i < ENN){
    int v = n_v[i], c = n_c[i];
    int s1 = starts[VN + v]        + atomicAdd(&fill[VN + v], 1);        listBuf[s1] = c; // NV
    int s2 = starts[2*VN + CN + c] + atomicAdd(&fill[2*VN + CN + c], 1); listBuf[s2] = v; // NC
  }
}

__global__ __launch_bounds__(256) void k_rdeg(const int* __restrict__ cnt, float* __restrict__ rdeg){
  int i = blockIdx.x*256 + threadIdx.x;
  if (i < SCN) rdeg[i] = 1.0f / (float)max(cnt[i], 1);
}

// ---------------- weight packing: W[K][N] f32 -> fragment-major bf16 ----------------
__global__ __launch_bounds__(256) void k_pack(const float* __restrict__ W, unsigned short* __restrict__ Wp, int K, int N){
  int o = blockIdx.x*256 + threadIdx.x;
  if (o >= K*N) return;
  int j = o & 7, l = (o>>3) & 63, frag = o >> 9;
  int K32 = K >> 5;
  int n0 = frag / K32, k0 = frag - n0*K32;
  int k = k0*32 + (l>>4)*8 + j, n = n0*16 + (l&15);
  Wp[o] = f2b(W[(size_t)k*N + n]);
}

// ---------------- GRU weight packing: per-(col-tile,gate) contiguous 12KB blocks ----------------
__global__ __launch_bounds__(256) void k_packgru(
    const float* __restrict__ Wih, const float* __restrict__ Whh,
    unsigned short* __restrict__ Wg)
{
  int idx = blockIdx.x*256 + threadIdx.x;
  if (idx >= 8*18432) return;
  int n0l = idx / 18432;
  int r = idx - n0l*18432;
  int g = r / 6144;
  int r2 = r - g*6144;
  int ih = (r2 < 4096) ? 1 : 0;
  int r3 = ih ? r2 : r2 - 4096;
  int k0 = r3 >> 9;
  int e = r3 & 511;
  int l = e >> 3, j = e & 7;
  int k = k0*32 + (l>>4)*8 + j;
  int n = g*128 + n0l*16 + (l&15);
  float v = ih ? Wih[(size_t)k*384 + n] : Whh[(size_t)k*384 + n];
  Wg[idx] = f2b(v);
}

__global__ __launch_bounds__(256) void k_init(const float* __restrict__ ini, unsigned short* __restrict__ emb, int total){
  int i = blockIdx.x*256 + threadIdx.x;
  if (i < total) emb[i] = f2b(ini[i & (DD-1)] * 0.08838834764831845f); // 1/sqrt(128)
}

// ---------------- dual two-layer MLP: 32 rows/wave, 8KB LDS/wave, bf16 X ----------------
__global__ __launch_bounds__(256) void k_mlp2dual(
    const unsigned short* __restrict__ X,
    const unsigned short* __restrict__ W1p, const float* __restrict__ b1p,
    const unsigned short* __restrict__ W2p, const float* __restrict__ b2p,
    const unsigned short* __restrict__ W1n, const float* __restrict__ b1n,
    const unsigned short* __restrict__ W2n, const float* __restrict__ b2n,
    unsigned short* __restrict__ Hp, unsigned short* __restrict__ Hn, int M)
{
  __shared__ __align__(16) char smem[32768];
  int t = threadIdx.x, lane = t & 63, wid = t >> 6;
  int r0 = blockIdx.x*128 + wid*32;
  if (r0 >= M) return;  // per-wave LDS only; no block barriers
  char* sW = smem + wid*8192;   // [32][128] bf16 swizzled; reused X -> H1 -> out
  int row16 = lane & 15, hq = lane >> 4, col0 = row16;

  // stage 32 rows of X (bf16, coalesced uint4) -> swizzled
  #pragma unroll
  for (int q=0;q<8;q++){
    int i = q*64 + lane; int row = i >> 4, cb = i & 15;
    int gr = r0 + row; if (gr >= M) gr = M-1;
    uint4 u = *(const uint4*)&X[(size_t)gr*DD + cb*8];
    *(uint4*)&sW[row*256 + ((cb^(row&7))<<4)] = u;
  }
  bf16x8 aX[2][4];
  #pragma unroll
  for (int tt=0;tt<2;tt++){
    int rowl = tt*16 + row16;
    #pragma unroll
    for (int k0=0;k0<4;k0++)
      aX[tt][k0] = *(const bf16x8*)&sW[rowl*256 + (((k0*4+hq)^(rowl&7))<<4)];
  }
  #pragma unroll
  for (int pn=0; pn<2; pn++){
    const unsigned short* W1 = pn? W1n : W1p; const float* b1 = pn? b1n : b1p;
    const unsigned short* W2 = pn? W2n : W2p; const float* b2 = pn? b2n : b2p;
    unsigned short* Hout = pn? Hn : Hp;
    // ---- layer 1: relu(X@W1+b1) -> sW ----
    bf16x8 wn[4];
    #pragma unroll
    for (int k0=0;k0<4;k0++) wn[k0] = *(const bf16x8*)&W1[((size_t)k0*64+lane)*8];
    #pragma unroll
    for (int n0=0;n0<8;n0++){
      bf16x8 wc[4];
      #pragma unroll
      for (int k0=0;k0<4;k0++) wc[k0] = wn[k0];
      if (n0 < 7){
        #pragma unroll
        for (int k0=0;k0<4;k0++) wn[k0] = *(const bf16x8*)&W1[((size_t)((n0+1)*4+k0)*64+lane)*8];
      }
      f32x4 acc[2] = {{0,0,0,0},{0,0,0,0}};
      #pragma unroll
      for (int k0=0;k0<4;k0++)
        #pragma unroll
        for (int tt=0;tt<2;tt++)
          acc[tt] = __builtin_amdgcn_mfma_f32_16x16x32_bf16(aX[tt][k0], wc[k0], acc[tt], 0,0,0);
      int col = n0*16 + col0;
      float bb = b1[col];
      #pragma unroll
      for (int tt=0;tt<2;tt++)
        #pragma unroll
        for (int r=0;r<4;r++){
          float v = fmaxf(acc[tt][r]+bb, 0.f);
          int rowl = tt*16 + hq*4 + r;
          *(unsigned short*)&sW[rowl*256 + (((col>>3)^(rowl&7))<<4) + (col&7)*2] = f2b(v);
        }
    }
    // ---- layer 2: H@W2+b2 ----
    bf16x8 aH[2][4];
    #pragma unroll
    for (int tt=0;tt<2;tt++){
      int rowl = tt*16 + row16;
      #pragma unroll
      for (int k0=0;k0<4;k0++)
        aH[tt][k0] = *(const bf16x8*)&sW[rowl*256 + (((k0*4+hq)^(rowl&7))<<4)];
    }
    #pragma unroll
    for (int k0=0;k0<4;k0++) wn[k0] = *(const bf16x8*)&W2[((size_t)k0*64+lane)*8];
    #pragma unroll
    for (int n0=0;n0<8;n0++){
      bf16x8 wc[4];
      #pragma unroll
      for (int k0=0;k0<4;k0++) wc[k0] = wn[k0];
      if (n0 < 7){
        #pragma unroll
        for (int k0=0;k0<4;k0++) wn[k0] = *(const bf16x8*)&W2[((size_t)((n0+1)*4+k0)*64+lane)*8];
      }
      f32x4 acc[2] = {{0,0,0,0},{0,0,0,0}};
      #pragma unroll
      for (int k0=0;k0<4;k0++)
        #pragma unroll
        for (int tt=0;tt<2;tt++)
          acc[tt] = __builtin_amdgcn_mfma_f32_16x16x32_bf16(aH[tt][k0], wc[k0], acc[tt], 0,0,0);
      int col = n0*16 + col0;
      float bb = b2[col];
      #pragma unroll
      for (int tt=0;tt<2;tt++)
        #pragma unroll
        for (int r=0;r<4;r++){
          int rowl = tt*16 + hq*4 + r;
          *(unsigned short*)&sW[rowl*256 + (((col>>3)^(rowl&7))<<4) + (col&7)*2] = f2b(acc[tt][r]+bb);
        }
    }
    // cooperative (within-wave) coalesced store of 32 rows
    #pragma unroll
    for (int q=0;q<8;q++){
      int i = lane + q*64; int rowl = i>>4, cb = i&15;
      int grow = r0 + rowl;
      if (grow < M)
        *(uint4*)&Hout[(size_t)grow*DD + cb*8] = *(const uint4*)&sW[rowl*256 + ((cb^(rowl&7))<<4)];
    }
  }
}

// ---------------- CSR gather-mean aggregation: 16 lanes per destination ----------------
__global__ __launch_bounds__(256) void k_aggr(
    const unsigned short* __restrict__ Hp, const unsigned short* __restrict__ Hn,
    const int* __restrict__ starts, const float* __restrict__ rdeg, const int* __restrict__ listBuf,
    unsigned short* __restrict__ Xg, int baseP, int baseN, int M)
{
  int d = blockIdx.x*16 + (threadIdx.x >> 4);
  if (d >= M) return;
  int l16 = threadIdx.x & 15;
  float a[8];
  #pragma unroll
  for (int j=0;j<8;j++) a[j]=0.f;
  int s = starts[baseP + d], e = starts[baseP + d + 1];
  for (int q=s; q<e; q++){
    int src = listBuf[q];
    uint4 u = *(const uint4*)&Hp[(size_t)src*DD + l16*8];
    a[0]+=b2f((unsigned short)u.x); a[1]+=b2f((unsigned short)(u.x>>16));
    a[2]+=b2f((unsigned short)u.y); a[3]+=b2f((unsigned short)(u.y>>16));
    a[4]+=b2f((unsigned short)u.z); a[5]+=b2f((unsigned short)(u.z>>16));
    a[6]+=b2f((unsigned short)u.w); a[7]+=b2f((unsigned short)(u.w>>16));
  }
  float rp = rdeg[baseP + d];
  uint4 o;
  o.x = (unsigned)f2b(a[0]*rp) | ((unsigned)f2b(a[1]*rp)<<16);
  o.y = (unsigned)f2b(a[2]*rp) | ((unsigned)f2b(a[3]*rp)<<16);
  o.z = (unsigned)f2b(a[4]*rp) | ((unsigned)f2b(a[5]*rp)<<16);
  o.w = (unsigned)f2b(a[6]*rp) | ((unsigned)f2b(a[7]*rp)<<16);
  *(uint4*)&Xg[(size_t)d*(2*DD) + l16*8] = o;
  #pragma unroll
  for (int j=0;j<8;j++) a[j]=0.f;
  s = starts[baseN + d]; e = starts[baseN + d + 1];
  for (int q=s; q<e; q++){
    int src = listBuf[q];
    uint4 u = *(const uint4*)&Hn[(size_t)src*DD + l16*8];
    a[0]+=b2f((unsigned short)u.x); a[1]+=b2f((unsigned short)(u.x>>16));
    a[2]+=b2f((unsigned short)u.y); a[3]+=b2f((unsigned short)(u.y>>16));
    a[4]+=b2f((unsigned short)u.z); a[5]+=b2f((unsigned short)(u.z>>16));
    a[6]+=b2f((unsigned short)u.w); a[7]+=b2f((unsigned short)(u.w>>16));
  }
  float rn = rdeg[baseN + d];
  o.x = (unsigned)f2b(a[0]*rn) | ((unsigned)f2b(a[1]*rn)<<16);
  o.y = (unsigned)f2b(a[2]*rn) | ((unsigned)f2b(a[3]*rn)<<16);
  o.z = (unsigned)f2b(a[4]*rn) | ((unsigned)f2b(a[5]*rn)<<16);
  o.w = (unsigned)f2b(a[6]*rn) | ((unsigned)f2b(a[7]*rn)<<16);
  *(uint4*)&Xg[(size_t)d*(2*DD) + DD + l16*8] = o;
}

// ---------------- fused GRU: weight-stationary col-group, barrier-free row streaming ----------------
// Block (cg, rg): 256 threads = 4 waves. cg owns col-tiles {2cg, 2cg+1}: 72KB of packed
// weights staged into LDS ONCE. Each wave then independently grid-strides 16-row tiles
// (no further barriers): load aX/aH -> 72 MFMA from LDS-resident weights -> epilogue.
__global__ __launch_bounds__(256) void k_gru(
    const unsigned short* __restrict__ hR, unsigned short* __restrict__ hW,
    const unsigned short* __restrict__ Xg,
    const unsigned short* __restrict__ Wg,
    const float* __restrict__ bih, const float* __restrict__ bhh,
    int M, int nrg)
{
  __shared__ __align__(16) char sW[73728];
  int t = threadIdx.x, lane = t & 63, wid = t >> 6;
  int cg = blockIdx.x & 3;
  int rg = blockIdx.x >> 2;
  int row16 = lane & 15, hq = lane >> 4, col0 = row16;
  int kb = hq*8;
  // one-time weight staging: 72KB = 4608 16B slots; reg-staged in chunks of 3
  {
    const char* src = (const char*)Wg + (size_t)cg*73728;
    #pragma unroll 1
    for (int i = 0; i < 18; i += 3){
      size_t s0 = ((size_t)(i  )*256 + t)*16;
      size_t s1 = ((size_t)(i+1)*256 + t)*16;
      size_t s2 = ((size_t)(i+2)*256 + t)*16;
      uint4 a = *(const uint4*)(src + s0);
      uint4 b = *(const uint4*)(src + s1);
      uint4 c = *(const uint4*)(src + s2);
      *(uint4*)(sW + s0) = a;
      *(uint4*)(sW + s1) = b;
      *(uint4*)(sW + s2) = c;
    }
  }
  __syncthreads();   // the only barrier
  int NRT = (M + 15) >> 4;
  int step = nrg*4;
  #pragma unroll 1
  for (int rt = rg*4 + wid; rt < NRT; rt += step){
    int r0 = rt*16;
    // A fragments for 16 rows (clamped)
    bf16x8 aX[8], aH[4];
    int arow = r0 + row16; if (arow >= M) arow = M-1;
    const unsigned short* xp = &Xg[(size_t)arow*(2*DD) + kb];
    #pragma unroll
    for (int k0=0;k0<8;k0++) aX[k0] = *(const bf16x8*)(xp + k0*32);
    const unsigned short* hpp = &hR[(size_t)arow*DD + kb];
    #pragma unroll
    for (int k0=0;k0<4;k0++) aH[k0] = *(const bf16x8*)(hpp + k0*32);
    #pragma unroll
    for (int j=0;j<2;j++){
      int n0l = cg*2 + j;
      int col = n0l*16 + col0;
      const char* wb = &sW[j*36864] + (size_t)lane*16;
      // old-h values for the blend
      f32x4 hp;
      #pragma unroll
      for (int r=0;r<4;r++){
        int g = r0 + hq*4 + r; if (g >= M) g = M-1;
        hp[r] = b2f(hR[(size_t)g*DD + col]);
      }
      f32x4 acc, rr, zz;
      // ---- R gate ----
      acc = (f32x4){0,0,0,0};
      #pragma unroll
      for (int k0=0;k0<8;k0++)
        acc = __builtin_amdgcn_mfma_f32_16x16x32_bf16(aX[k0], *(const bf16x8*)(wb + k0*1024), acc, 0,0,0);
      #pragma unroll
      for (int k0=0;k0<4;k0++)
        acc = __builtin_amdgcn_mfma_f32_16x16x32_bf16(aH[k0], *(const bf16x8*)(wb + 8192 + k0*1024), acc, 0,0,0);
      {
        float br = bih[col] + bhh[col];
        #pragma unroll
        for (int r=0;r<4;r++) rr[r] = sigm(acc[r] + br);
      }
      // ---- Z gate ----
      acc = (f32x4){0,0,0,0};
      #pragma unroll
      for (int k0=0;k0<8;k0++)
        acc = __builtin_amdgcn_mfma_f32_16x16x32_bf16(aX[k0], *(const bf16x8*)(wb + 12288 + k0*1024), acc, 0,0,0);
      #pragma unroll
      for (int k0=0;k0<4;k0++)
        acc = __builtin_amdgcn_mfma_f32_16x16x32_bf16(aH[k0], *(const bf16x8*)(wb + 12288 + 8192 + k0*1024), acc, 0,0,0);
      {
        float bz = bih[DD + col] + bhh[DD + col];
        #pragma unroll
        for (int r=0;r<4;r++) zz[r] = sigm(acc[r] + bz);
      }
      // ---- N gate (X and H parts separate) ----
      f32x4 nx = (f32x4){0,0,0,0}, nh = (f32x4){0,0,0,0};
      #pragma unroll
      for (int k0=0;k0<8;k0++)
        nx = __builtin_amdgcn_mfma_f32_16x16x32_bf16(aX[k0], *(const bf16x8*)(wb + 24576 + k0*1024), nx, 0,0,0);
      #pragma unroll
      for (int k0=0;k0<4;k0++)
        nh = __builtin_amdgcn_mfma_f32_16x16x32_bf16(aH[k0], *(const bf16x8*)(wb + 24576 + 8192 + k0*1024), nh, 0,0,0);
      {
        float bin = bih[2*DD + col], bhn = bhh[2*DD + col];
        #pragma unroll
        for (int r=0;r<4;r++){
          int g = r0 + hq*4 + r;
          if (g < M){
            float nn = tanhf(nx[r] + bin + rr[r]*(nh[r] + bhn));
            hW[(size_t)g*DD + col] = f2b((1.f - zz[r])*nn + zz[r]*hp[r]);
          }
        }
      }
    }
  }
}

// ---------------- per-graph mean readout ----------------
__global__ __launch_bounds__(256) void k_batchsum(
    const unsigned short* __restrict__ v_emb, const int* __restrict__ vb,
    float* __restrict__ g_sum, float* __restrict__ g_cnt)
{
  int c = threadIdx.x & (DD-1);
  int half = threadIdx.x >> 7;
  int rs = blockIdx.x*128 + half*64;
  if (rs >= VN) return;
  int re = rs + 64; if (re > VN) re = VN;
  float acc = 0.f, cnt = 0.f;
  int cur = vb[rs];
  for (int r = rs; r < re; r++){
    int b = vb[r];
    if (b != cur){
      atomicAdd(&g_sum[cur*DD + c], acc);
      if (c == 0) atomicAdd(&g_cnt[cur], cnt);
      acc = 0.f; cnt = 0.f; cur = b;
    }
    acc += b2f(v_emb[(size_t)r*DD + c]);
    cnt += 1.f;
  }
  atomicAdd(&g_sum[cur*DD + c], acc);
  if (c == 0) atomicAdd(&g_cnt[cur], cnt);
}

__global__ __launch_bounds__(128) void k_readout(
    const float* __restrict__ g_sum, const float* __restrict__ g_cnt,
    const float* __restrict__ W1, const float* __restrict__ b1,
    const float* __restrict__ W2, const float* __restrict__ b2,
    float* __restrict__ out)
{
  __shared__ float sg[DD];
  __shared__ float sr[DD];
  int b = blockIdx.x, c = threadIdx.x;
  float rc = 1.0f / fmaxf(g_cnt[b], 1.0f);
  sg[c] = g_sum[b*DD + c] * rc;
  __syncthreads();
  float a = b1[c];
  for (int k=0;k<DD;k++) a = fmaf(sg[k], W1[(size_t)k*DD + c], a);
  a = fmaxf(a, 0.f);
  sr[c] = a * W2[c];
  __syncthreads();
  for (int s=64; s>0; s>>=1){
    if (c < s) sr[c] += sr[c+s];
    __syncthreads();
  }
  if (c == 0) out[b] = sigm(sr[0] + b2[0]);
}

// ---------------- orchestration ----------------
extern "C" void kernel_launch(void* const* d_in, const int* in_sizes, int n_in,
                              void* d_out, int out_size, void* d_ws, size_t ws_size,
                              hipStream_t stream)
{
  const int* vE = (const int*)d_in[0];
  const int* cE = (const int*)d_in[1];
  const int* pE = (const int*)d_in[2];
  const int* nE = (const int*)d_in[3];
  const int* vb = (const int*)d_in[4];
  const float* v_init = (const float*)d_in[5];
  const float* c_init = (const float*)d_in[6];
  const float* mW1[4]; const float* mb1[4]; const float* mW2[4]; const float* mb2[4];
  for (int m=0;m<4;m++){
    mW1[m] = (const float*)d_in[7 + m*4 + 0];
    mb1[m] = (const float*)d_in[7 + m*4 + 1];
    mW2[m] = (const float*)d_in[7 + m*4 + 2];
    mb2[m] = (const float*)d_in[7 + m*4 + 3];
  }
  const float* gc_Wih = (const float*)d_in[23];
  const float* gc_Whh = (const float*)d_in[24];
  const float* gc_bih = (const float*)d_in[25];
  const float* gc_bhh = (const float*)d_in[26];
  const float* gv_Wih = (const float*)d_in[27];
  const float* gv_Whh = (const float*)d_in[28];
  const float* gv_bih = (const float*)d_in[29];
  const float* gv_bhh = (const float*)d_in[30];
  const float* ro_W1 = (const float*)d_in[31];
  const float* ro_b1 = (const float*)d_in[32];
  const float* ro_W2 = (const float*)d_in[33];
  const float* ro_b2 = (const float*)d_in[34];
  float* out = (float*)d_out;

  char* base = (char*)d_ws;
  size_t off = 0;
  auto alloc = [&](size_t n)->void*{ void* p = base + off; off += (n + 255) & ~(size_t)255; return p; };
  int* cnt4    = (int*)alloc((size_t)SCN*4);
  int* fill4   = (int*)alloc((size_t)SCN*4);
  int* starts  = (int*)alloc(((size_t)SCN+1)*4);
  int* bsum    = (int*)alloc(512*4);
  int* boff    = (int*)alloc(512*4);
  int* p_v     = (int*)alloc((size_t)EPN*4);
  int* p_c     = (int*)alloc((size_t)EPN*4);
  int* n_v     = (int*)alloc((size_t)ENN*4);
  int* n_c     = (int*)alloc((size_t)ENN*4);
  int* listBuf = (int*)alloc((size_t)2*(EPN+ENN)*4);
  float* rdeg4 = (float*)alloc((size_t)SCN*4);
  unsigned short* v_embA = (unsigned short*)alloc((size_t)VN*DD*2);
  unsigned short* v_embB = (unsigned short*)alloc((size_t)VN*DD*2);
  unsigned short* c_embA = (unsigned short*)alloc((size_t)CN*DD*2);
  unsigned short* c_embB = (unsigned short*)alloc((size_t)CN*DD*2);
  unsigned short* Hp = (unsigned short*)alloc((size_t)CN*DD*2);
  unsigned short* Hn = (unsigned short*)alloc((size_t)CN*DD*2);
  unsigned short* Xg = (unsigned short*)alloc((size_t)CN*2*DD*2);
  unsigned short* P_W1[4]; unsigned short* P_W2[4];
  for (int m=0;m<4;m++){
    P_W1[m] = (unsigned short*)alloc((size_t)DD*DD*2);
    P_W2[m] = (unsigned short*)alloc((size_t)DD*DD*2);
  }
  unsigned short* P_gc = (unsigned short*)alloc((size_t)8*18432*2);
  unsigned short* P_gv = (unsigned short*)alloc((size_t)8*18432*2);
  float* g_sum = (float*)alloc((size_t)BN*DD*4);
  float* g_cnt = (float*)alloc((size_t)BN*4);
  (void)in_sizes; (void)n_in; (void)out_size; (void)ws_size;

  hipMemsetAsync(cnt4, 0, (size_t)SCN*4, stream);
  hipMemsetAsync(fill4, 0, (size_t)SCN*4, stream);

  k_edges<<<(EPN+255)/256, 256, 0, stream>>>(vE, cE, pE, nE, p_v, p_c, n_v, n_c, cnt4);
  k_scan1<<<SC_NB, 256, 0, stream>>>(cnt4, starts, bsum);
  k_scan2<<<1, 512, 0, stream>>>(bsum, boff, starts + SCN);
  k_scan3<<<SC_NB, 256, 0, stream>>>(starts, boff);
  k_fill<<<(EPN+255)/256, 256, 0, stream>>>(p_v, p_c, n_v, n_c, starts, fill4, listBuf);
  k_rdeg<<<(SCN+255)/256, 256, 0, stream>>>(cnt4, rdeg4);

  for (int m=0;m<4;m++){
    k_pack<<<(DD*DD+255)/256, 256, 0, stream>>>(mW1[m], P_W1[m], DD, DD);
    k_pack<<<(DD*DD+255)/256, 256, 0, stream>>>(mW2[m], P_W2[m], DD, DD);
  }
  k_packgru<<<(8*18432+255)/256, 256, 0, stream>>>(gc_Wih, gc_Whh, P_gc);
  k_packgru<<<(8*18432+255)/256, 256, 0, stream>>>(gv_Wih, gv_Whh, P_gv);

  k_init<<<((size_t)VN*DD+255)/256, 256, 0, stream>>>(v_init, v_embA, VN*DD);
  k_init<<<((size_t)CN*DD+255)/256, 256, 0, stream>>>(c_init, c_embA, CN*DD);

  int mlpVb = (VN+127)/128, mlpCb = (CN+127)/128;
  int nrgC = 128, nrgV = 64;   // grids: 512 (2/CU) and 256 (1/CU)
  unsigned short* vc = v_embA; unsigned short* va = v_embB;
  unsigned short* cc = c_embA; unsigned short* ca = c_embB;
  for (int it=0; it<3; ++it){
    // ---- v -> c ----
    k_mlp2dual<<<mlpVb, 256, 0, stream>>>(vc, P_W1[0], mb1[0], P_W2[0], mb2[0],
                                                   P_W1[1], mb1[1], P_W2[1], mb2[1], Hp, Hn, VN);
    k_aggr<<<(CN+15)/16, 256, 0, stream>>>(Hp, Hn, starts, rdeg4, listBuf, Xg, 2*VN, 2*VN+CN, CN);
    k_gru<<<4*nrgC, 256, 0, stream>>>(cc, ca, Xg, P_gc, gc_bih, gc_bhh, CN, nrgC);
    { unsigned short* tmp = cc; cc = ca; ca = tmp; }
    // ---- c -> v ----
    k_mlp2dual<<<mlpCb, 256, 0, stream>>>(cc, P_W1[2], mb1[2], P_W2[2], mb2[2],
                                                   P_W1[3], mb1[3], P_W2[3], mb2[3], Hp, Hn, CN);
    k_aggr<<<(VN+15)/16, 256, 0, stream>>>(Hp, Hn, starts, rdeg4, listBuf, Xg, 0, VN, VN);
    k_gru<<<4*nrgV, 256, 0, stream>>>(vc, va, Xg, P_gv, gv_bih, gv_bhh, VN, nrgV);
    { unsigned short* tmp = vc; vc = va; va = tmp; }
  }

  hipMemsetAsync(g_sum, 0, (size_t)BN*DD*4, stream);
  hipMemsetAsync(g_cnt, 0, (size_t)BN*4, stream);
  k_batchsum<<<(VN+127)/128, 256, 0, stream>>>(vc, vb, g_sum, g_cnt);
  k_readout<<<BN, 128, 0, stream>>>(g_sum, g_cnt, ro_W1, ro_b1, ro_W2, ro_b2, out);
}

// Round 14
// 962.166 us; speedup vs baseline: 1.0073x; 1.0073x over previous
//
#include <hip/hip_runtime.h>

#define VN 30000
#define CN 120000
#define EPN 180000
#define ENN 180000
#define DD 128
#define BN 32
#define SCN (2*VN + 2*CN)          // 300000 concatenated degree rows: PV | NV | PC | NC
#define SC_NB ((SCN + 1023) / 1024) // 293 scan blocks

using bf16x8 = __attribute__((ext_vector_type(8))) short;
using f32x4  = __attribute__((ext_vector_type(4))) float;

static __device__ __forceinline__ float sigm(float x){ return 1.0f/(1.0f+__expf(-x)); }
static __device__ __forceinline__ unsigned short f2b(float f){
  unsigned int u = __float_as_uint(f);
  unsigned int r = u + 0x7fffu + ((u>>16)&1u);
  return (unsigned short)(r>>16);
}
static __device__ __forceinline__ float b2f(unsigned short s){
  return __uint_as_float(((unsigned int)s)<<16);
}

// ---------------- edge endpoints + integer degree counts ----------------
__global__ __launch_bounds__(256) void k_edges(
    const int* __restrict__ vE, const int* __restrict__ cE,
    const int* __restrict__ pE, const int* __restrict__ nE,
    int* __restrict__ p_v, int* __restrict__ p_c,
    int* __restrict__ n_v, int* __restrict__ n_c,
    int* __restrict__ cnt)
{
  int i = blockIdx.x*256 + threadIdx.x;
  if (i < EPN){
    int e = pE[i]; int v = vE[e], c = cE[e];
    p_v[i] = v; p_c[i] = c;
    atomicAdd(&cnt[v], 1); atomicAdd(&cnt[2*VN + c], 1);
  }
  if (i < ENN){
    int e = nE[i]; int v = vE[e], c = cE[e];
    n_v[i] = v; n_c[i] = c;
    atomicAdd(&cnt[VN + v], 1); atomicAdd(&cnt[2*VN + CN + c], 1);
  }
}

// ---------------- 3-phase exclusive scan over cnt[SCN] ----------------
__global__ __launch_bounds__(256) void k_scan1(const int* __restrict__ cnt, int* __restrict__ part, int* __restrict__ bsum){
  __shared__ int s[256];
  int b = blockIdx.x, t = threadIdx.x;
  int base = b*1024 + t*4;
  int v0 = (base+0<SCN)?cnt[base+0]:0;
  int v1 = (base+1<SCN)?cnt[base+1]:0;
  int v2 = (base+2<SCN)?cnt[base+2]:0;
  int v3 = (base+3<SCN)?cnt[base+3]:0;
  int loc = v0+v1+v2+v3;
  s[t] = loc; __syncthreads();
  for (int off=1; off<256; off<<=1){
    int x = (t>=off)? s[t-off] : 0;
    __syncthreads();
    s[t] += x;
    __syncthreads();
  }
  int excl = s[t]-loc;
  if (t==255) bsum[b] = s[255];
  if (base  <SCN) part[base  ] = excl;
  if (base+1<SCN) part[base+1] = excl+v0;
  if (base+2<SCN) part[base+2] = excl+v0+v1;
  if (base+3<SCN) part[base+3] = excl+v0+v1+v2;
}
__global__ __launch_bounds__(512) void k_scan2(const int* __restrict__ bsum, int* __restrict__ boff, int* __restrict__ total_out){
  __shared__ int s[512];
  int t = threadIdx.x;
  int v = (t<SC_NB)? bsum[t] : 0;
  s[t]=v; __syncthreads();
  for (int off=1; off<512; off<<=1){
    int x = (t>=off)? s[t-off] : 0;
    __syncthreads();
    s[t]+=x;
    __syncthreads();
  }
  if (t<SC_NB) boff[t] = s[t]-v;
  if (t==511) total_out[0] = s[511];
}
__global__ __launch_bounds__(256) void k_scan3(int* __restrict__ part, const int* __restrict__ boff){
  int b = blockIdx.x; int base = b*1024 + threadIdx.x*4; int o = boff[b];
  #pragma unroll
  for (int i=0;i<4;i++) if (base+i < SCN) part[base+i] += o;
}

// ---------------- CSR bucket fill ----------------
__global__ __launch_bounds__(256) void k_fill(
    const int* __restrict__ p_v, const int* __restrict__ p_c,
    const int* __restrict__ n_v, const int* __restrict__ n_c,
    const int* __restrict__ starts, int* __restrict__ fill, int* __restrict__ listBuf)
{
  int i = blockIdx.x*256 + threadIdx.x;
  if (i < EPN){
    int v = p_v[i], c = p_c[i];
    int s1 = starts[v]        + atomicAdd(&fill[v], 1);          listBuf[s1] = c; // PV
    int s2 = starts[2*VN + c] + atomicAdd(&fill[2*VN + c], 1);   listBuf[s2] = v; // PC
  }
  if (i < ENN){
    int v = n_v[i], c = n_c[i];
    int s1 = starts[VN + v]        + atomicAdd(&fill[VN + v], 1);        listBuf[s1] = c; // NV
    int s2 = starts[2*VN + CN + c] + atomicAdd(&fill[2*VN + CN + c], 1); listBuf[s2] = v; // NC
  }
}

__global__ __launch_bounds__(256) void k_rdeg(const int* __restrict__ cnt, float* __restrict__ rdeg){
  int i = blockIdx.x*256 + threadIdx.x;
  if (i < SCN) rdeg[i] = 1.0f / (float)max(cnt[i], 1);
}

// ---------------- weight packing: W[K][N] f32 -> fragment-major bf16 ----------------
__global__ __launch_bounds__(256) void k_pack(const float* __restrict__ W, unsigned short* __restrict__ Wp, int K, int N){
  int o = blockIdx.x*256 + threadIdx.x;
  if (o >= K*N) return;
  int j = o & 7, l = (o>>3) & 63, frag = o >> 9;
  int K32 = K >> 5;
  int n0 = frag / K32, k0 = frag - n0*K32;
  int k = k0*32 + (l>>4)*8 + j, n = n0*16 + (l&15);
  Wp[o] = f2b(W[(size_t)k*N + n]);
}

// ---------------- GRU weight packing: per-(col-tile,gate) contiguous 12KB blocks ----------------
__global__ __launch_bounds__(256) void k_packgru(
    const float* __restrict__ Wih, const float* __restrict__ Whh,
    unsigned short* __restrict__ Wg)
{
  int idx = blockIdx.x*256 + threadIdx.x;
  if (idx >= 8*18432) return;
  int n0l = idx / 18432;
  int r = idx - n0l*18432;
  int g = r / 6144;
  int r2 = r - g*6144;
  int ih = (r2 < 4096) ? 1 : 0;
  int r3 = ih ? r2 : r2 - 4096;
  int k0 = r3 >> 9;
  int e = r3 & 511;
  int l = e >> 3, j = e & 7;
  int k = k0*32 + (l>>4)*8 + j;
  int n = g*128 + n0l*16 + (l&15);
  float v = ih ? Wih[(size_t)k*384 + n] : Whh[(size_t)k*384 + n];
  Wg[idx] = f2b(v);
}

__global__ __launch_bounds__(256) void k_init(const float* __restrict__ ini, unsigned short* __restrict__ emb, int total){
  int i = blockIdx.x*256 + threadIdx.x;
  if (i < total) emb[i] = f2b(ini[i & (DD-1)] * 0.08838834764831845f); // 1/sqrt(128)
}

// ---------------- dual two-layer MLP: 32 rows/wave, 8KB LDS/wave, bf16 X ----------------
__global__ __launch_bounds__(256) void k_mlp2dual(
    const unsigned short* __restrict__ X,
    const unsigned short* __restrict__ W1p, const float* __restrict__ b1p,
    const unsigned short* __restrict__ W2p, const float* __restrict__ b2p,
    const unsigned short* __restrict__ W1n, const float* __restrict__ b1n,
    const unsigned short* __restrict__ W2n, const float* __restrict__ b2n,
    unsigned short* __restrict__ Hp, unsigned short* __restrict__ Hn, int M)
{
  __shared__ __align__(16) char smem[32768];
  int t = threadIdx.x, lane = t & 63, wid = t >> 6;
  int r0 = blockIdx.x*128 + wid*32;
  if (r0 >= M) return;  // per-wave LDS only; no block barriers
  char* sW = smem + wid*8192;   // [32][128] bf16 swizzled; reused X -> H1 -> out
  int row16 = lane & 15, hq = lane >> 4, col0 = row16;

  // stage 32 rows of X (bf16, coalesced uint4) -> swizzled
  #pragma unroll
  for (int q=0;q<8;q++){
    int i = q*64 + lane; int row = i >> 4, cb = i & 15;
    int gr = r0 + row; if (gr >= M) gr = M-1;
    uint4 u = *(const uint4*)&X[(size_t)gr*DD + cb*8];
    *(uint4*)&sW[row*256 + ((cb^(row&7))<<4)] = u;
  }
  bf16x8 aX[2][4];
  #pragma unroll
  for (int tt=0;tt<2;tt++){
    int rowl = tt*16 + row16;
    #pragma unroll
    for (int k0=0;k0<4;k0++)
      aX[tt][k0] = *(const bf16x8*)&sW[rowl*256 + (((k0*4+hq)^(rowl&7))<<4)];
  }
  #pragma unroll
  for (int pn=0; pn<2; pn++){
    const unsigned short* W1 = pn? W1n : W1p; const float* b1 = pn? b1n : b1p;
    const unsigned short* W2 = pn? W2n : W2p; const float* b2 = pn? b2n : b2p;
    unsigned short* Hout = pn? Hn : Hp;
    // ---- layer 1: relu(X@W1+b1) -> sW ----
    bf16x8 wn[4];
    #pragma unroll
    for (int k0=0;k0<4;k0++) wn[k0] = *(const bf16x8*)&W1[((size_t)k0*64+lane)*8];
    #pragma unroll
    for (int n0=0;n0<8;n0++){
      bf16x8 wc[4];
      #pragma unroll
      for (int k0=0;k0<4;k0++) wc[k0] = wn[k0];
      if (n0 < 7){
        #pragma unroll
        for (int k0=0;k0<4;k0++) wn[k0] = *(const bf16x8*)&W1[((size_t)((n0+1)*4+k0)*64+lane)*8];
      }
      f32x4 acc[2] = {{0,0,0,0},{0,0,0,0}};
      #pragma unroll
      for (int k0=0;k0<4;k0++)
        #pragma unroll
        for (int tt=0;tt<2;tt++)
          acc[tt] = __builtin_amdgcn_mfma_f32_16x16x32_bf16(aX[tt][k0], wc[k0], acc[tt], 0,0,0);
      int col = n0*16 + col0;
      float bb = b1[col];
      #pragma unroll
      for (int tt=0;tt<2;tt++)
        #pragma unroll
        for (int r=0;r<4;r++){
          float v = fmaxf(acc[tt][r]+bb, 0.f);
          int rowl = tt*16 + hq*4 + r;
          *(unsigned short*)&sW[rowl*256 + (((col>>3)^(rowl&7))<<4) + (col&7)*2] = f2b(v);
        }
    }
    // ---- layer 2: H@W2+b2 ----
    bf16x8 aH[2][4];
    #pragma unroll
    for (int tt=0;tt<2;tt++){
      int rowl = tt*16 + row16;
      #pragma unroll
      for (int k0=0;k0<4;k0++)
        aH[tt][k0] = *(const bf16x8*)&sW[rowl*256 + (((k0*4+hq)^(rowl&7))<<4)];
    }
    #pragma unroll
    for (int k0=0;k0<4;k0++) wn[k0] = *(const bf16x8*)&W2[((size_t)k0*64+lane)*8];
    #pragma unroll
    for (int n0=0;n0<8;n0++){
      bf16x8 wc[4];
      #pragma unroll
      for (int k0=0;k0<4;k0++) wc[k0] = wn[k0];
      if (n0 < 7){
        #pragma unroll
        for (int k0=0;k0<4;k0++) wn[k0] = *(const bf16x8*)&W2[((size_t)((n0+1)*4+k0)*64+lane)*8];
      }
      f32x4 acc[2] = {{0,0,0,0},{0,0,0,0}};
      #pragma unroll
      for (int k0=0;k0<4;k0++)
        #pragma unroll
        for (int tt=0;tt<2;tt++)
          acc[tt] = __builtin_amdgcn_mfma_f32_16x16x32_bf16(aH[tt][k0], wc[k0], acc[tt], 0,0,0);
      int col = n0*16 + col0;
      float bb = b2[col];
      #pragma unroll
      for (int tt=0;tt<2;tt++)
        #pragma unroll
        for (int r=0;r<4;r++){
          int rowl = tt*16 + hq*4 + r;
          *(unsigned short*)&sW[rowl*256 + (((col>>3)^(rowl&7))<<4) + (col&7)*2] = f2b(acc[tt][r]+bb);
        }
    }
    // cooperative (within-wave) coalesced store of 32 rows
    #pragma unroll
    for (int q=0;q<8;q++){
      int i = lane + q*64; int rowl = i>>4, cb = i&15;
      int grow = r0 + rowl;
      if (grow < M)
        *(uint4*)&Hout[(size_t)grow*DD + cb*8] = *(const uint4*)&sW[rowl*256 + ((cb^(rowl&7))<<4)];
    }
  }
}

// ---------------- CSR gather-mean aggregation: 16 lanes/dest, interleaved p/n chains ----------------
__global__ __launch_bounds__(256) void k_aggr(
    const unsigned short* __restrict__ Hp, const unsigned short* __restrict__ Hn,
    const int* __restrict__ starts, const float* __restrict__ rdeg, const int* __restrict__ listBuf,
    unsigned short* __restrict__ Xg, int baseP, int baseN, int M)
{
  int d = blockIdx.x*16 + (threadIdx.x >> 4);
  if (d >= M) return;
  int l16 = threadIdx.x & 15;
  int qp = starts[baseP + d], ep = starts[baseP + d + 1];
  int qn = starts[baseN + d], en = starts[baseN + d + 1];
  float ap[8], an[8];
  #pragma unroll
  for (int j=0;j<8;j++){ ap[j]=0.f; an[j]=0.f; }
  // interleaved: both gather chains in flight
  while (qp < ep && qn < en){
    int sp_ = listBuf[qp++];
    int sn_ = listBuf[qn++];
    uint4 up = *(const uint4*)&Hp[(size_t)sp_*DD + l16*8];
    uint4 un = *(const uint4*)&Hn[(size_t)sn_*DD + l16*8];
    ap[0]+=b2f((unsigned short)up.x); ap[1]+=b2f((unsigned short)(up.x>>16));
    ap[2]+=b2f((unsigned short)up.y); ap[3]+=b2f((unsigned short)(up.y>>16));
    ap[4]+=b2f((unsigned short)up.z); ap[5]+=b2f((unsigned short)(up.z>>16));
    ap[6]+=b2f((unsigned short)up.w); ap[7]+=b2f((unsigned short)(up.w>>16));
    an[0]+=b2f((unsigned short)un.x); an[1]+=b2f((unsigned short)(un.x>>16));
    an[2]+=b2f((unsigned short)un.y); an[3]+=b2f((unsigned short)(un.y>>16));
    an[4]+=b2f((unsigned short)un.z); an[5]+=b2f((unsigned short)(un.z>>16));
    an[6]+=b2f((unsigned short)un.w); an[7]+=b2f((unsigned short)(un.w>>16));
  }
  while (qp < ep){
    int src = listBuf[qp++];
    uint4 u = *(const uint4*)&Hp[(size_t)src*DD + l16*8];
    ap[0]+=b2f((unsigned short)u.x); ap[1]+=b2f((unsigned short)(u.x>>16));
    ap[2]+=b2f((unsigned short)u.y); ap[3]+=b2f((unsigned short)(u.y>>16));
    ap[4]+=b2f((unsigned short)u.z); ap[5]+=b2f((unsigned short)(u.z>>16));
    ap[6]+=b2f((unsigned short)u.w); ap[7]+=b2f((unsigned short)(u.w>>16));
  }
  while (qn < en){
    int src = listBuf[qn++];
    uint4 u = *(const uint4*)&Hn[(size_t)src*DD + l16*8];
    an[0]+=b2f((unsigned short)u.x); an[1]+=b2f((unsigned short)(u.x>>16));
    an[2]+=b2f((unsigned short)u.y); an[3]+=b2f((unsigned short)(u.y>>16));
    an[4]+=b2f((unsigned short)u.z); an[5]+=b2f((unsigned short)(u.z>>16));
    an[6]+=b2f((unsigned short)u.w); an[7]+=b2f((unsigned short)(u.w>>16));
  }
  float rp = rdeg[baseP + d];
  float rn = rdeg[baseN + d];
  uint4 o;
  o.x = (unsigned)f2b(ap[0]*rp) | ((unsigned)f2b(ap[1]*rp)<<16);
  o.y = (unsigned)f2b(ap[2]*rp) | ((unsigned)f2b(ap[3]*rp)<<16);
  o.z = (unsigned)f2b(ap[4]*rp) | ((unsigned)f2b(ap[5]*rp)<<16);
  o.w = (unsigned)f2b(ap[6]*rp) | ((unsigned)f2b(ap[7]*rp)<<16);
  *(uint4*)&Xg[(size_t)d*(2*DD) + l16*8] = o;
  o.x = (unsigned)f2b(an[0]*rn) | ((unsigned)f2b(an[1]*rn)<<16);
  o.y = (unsigned)f2b(an[2]*rn) | ((unsigned)f2b(an[3]*rn)<<16);
  o.z = (unsigned)f2b(an[4]*rn) | ((unsigned)f2b(an[5]*rn)<<16);
  o.w = (unsigned)f2b(an[6]*rn) | ((unsigned)f2b(an[7]*rn)<<16);
  *(uint4*)&Xg[(size_t)d*(2*DD) + DD + l16*8] = o;
}

// ---------------- fused GRU: reg-staged 2-deep weight pipeline, bf16 h ----------------
// 4 waves x 32 rows = 128 rows/block. 24 sub-phases (col-tile x gate), 12KB weights each.
// Phase sp: publish set[sp&1] -> barrier -> reload set[sp&1] for sp+2 -> compute.
// Loads get TWO compute phases (+2 barriers) of slack to cover L2/HBM latency.
__global__ __launch_bounds__(256) void k_gru(
    const unsigned short* __restrict__ hR, unsigned short* __restrict__ hW,
    const unsigned short* __restrict__ Xg,
    const unsigned short* __restrict__ Wg,
    const float* __restrict__ bih, const float* __restrict__ bhh,
    int M)
{
  __shared__ __align__(16) char sW[2][12288];
  int t = threadIdx.x, lane = t & 63;
  int wid = t >> 6;
  int r0 = blockIdx.x*128 + wid*32;
  int row16 = lane & 15, hq = lane >> 4, col0 = row16;
  int kb = hq*8;
  // A fragments (rows clamped; no early return — barriers below)
  bf16x8 aX[2][8];
  bf16x8 aH[2][4];
  #pragma unroll
  for (int tt=0;tt<2;tt++){
    int row = r0 + tt*16 + row16; if (row >= M) row = M-1;
    const unsigned short* xp = &Xg[(size_t)row*(2*DD) + kb];
    #pragma unroll
    for (int k0=0;k0<8;k0++) aX[tt][k0] = *(const bf16x8*)(xp + k0*32);
    const unsigned short* hp = &hR[(size_t)row*DD + kb];
    #pragma unroll
    for (int k0=0;k0<4;k0++) aH[tt][k0] = *(const bf16x8*)(hp + k0*32);
  }
  // each thread owns 3x16B slices of the 12KB sub-block; two register sets (2-deep)
  const char* wsrc = (const char*)Wg + (size_t)(wid*3)*1024 + lane*16;
  char* d0 = &sW[0][(size_t)(wid*3)*1024 + lane*16];
  char* d1 = &sW[1][(size_t)(wid*3)*1024 + lane*16];
  uint4 wA0, wA1, wA2, wB0, wB1, wB2;
  wA0 = *(const uint4*)(wsrc);
  wA1 = *(const uint4*)(wsrc + 1024);
  wA2 = *(const uint4*)(wsrc + 2048);
  wB0 = *(const uint4*)(wsrc + 12288);
  wB1 = *(const uint4*)(wsrc + 12288 + 1024);
  wB2 = *(const uint4*)(wsrc + 12288 + 2048);
  f32x4 rr0, rr1, zz0, zz1, hp0, hp1;
  #pragma unroll 1
  for (int sp = 0; sp < 24; sp++){
    int cur = sp & 1;
    // publish this sub-phase's weights (loaded 2 phases ago / prologue)
    if (!cur){
      *(uint4*)(d0)        = wA0;
      *(uint4*)(d0 + 1024) = wA1;
      *(uint4*)(d0 + 2048) = wA2;
    } else {
      *(uint4*)(d1)        = wB0;
      *(uint4*)(d1 + 1024) = wB1;
      *(uint4*)(d1 + 2048) = wB2;
    }
    __syncthreads();
    // reload the just-published set for sp+2: two full phases of slack
    if (sp < 22){
      const char* src = wsrc + (size_t)(sp+2)*12288;
      if (!cur){
        wA0 = *(const uint4*)(src);
        wA1 = *(const uint4*)(src + 1024);
        wA2 = *(const uint4*)(src + 2048);
      } else {
        wB0 = *(const uint4*)(src);
        wB1 = *(const uint4*)(src + 1024);
        wB2 = *(const uint4*)(src + 2048);
      }
    }
    int n0l = sp / 3;
    int gate = sp - n0l*3;
    int col = n0l*16 + col0;
    const char* wb = &sW[cur][0] + lane*16;
    // X-part and H-part accumulated separately (N gate needs them split)
    f32x4 xa0 = {0,0,0,0}, xa1 = {0,0,0,0};
    f32x4 ha0 = {0,0,0,0}, ha1 = {0,0,0,0};
    #pragma unroll
    for (int k0=0;k0<8;k0++){
      bf16x8 w = *(const bf16x8*)(wb + k0*1024);
      xa0 = __builtin_amdgcn_mfma_f32_16x16x32_bf16(aX[0][k0], w, xa0, 0,0,0);
      xa1 = __builtin_amdgcn_mfma_f32_16x16x32_bf16(aX[1][k0], w, xa1, 0,0,0);
    }
    #pragma unroll
    for (int k0=0;k0<4;k0++){
      bf16x8 w = *(const bf16x8*)(wb + 8192 + k0*1024);
      ha0 = __builtin_amdgcn_mfma_f32_16x16x32_bf16(aH[0][k0], w, ha0, 0,0,0);
      ha1 = __builtin_amdgcn_mfma_f32_16x16x32_bf16(aH[1][k0], w, ha1, 0,0,0);
    }
    if (gate == 0){
      float br = bih[col] + bhh[col];
      #pragma unroll
      for (int r=0;r<4;r++){
        rr0[r] = sigm(xa0[r] + ha0[r] + br);
        rr1[r] = sigm(xa1[r] + ha1[r] + br);
      }
      // prefetch old-h epilogue values (ready 2 sub-phases later at the N gate)
      #pragma unroll
      for (int r=0;r<4;r++){
        int g0 = r0 + hq*4 + r;      if (g0 >= M) g0 = M-1;
        int g1 = r0 + 16 + hq*4 + r; if (g1 >= M) g1 = M-1;
        hp0[r] = b2f(hR[(size_t)g0*DD + col]);
        hp1[r] = b2f(hR[(size_t)g1*DD + col]);
      }
    } else if (gate == 1){
      float bz = bih[DD + col] + bhh[DD + col];
      #pragma unroll
      for (int r=0;r<4;r++){
        zz0[r] = sigm(xa0[r] + ha0[r] + bz);
        zz1[r] = sigm(xa1[r] + ha1[r] + bz);
      }
    } else {
      float bin = bih[2*DD + col], bhn = bhh[2*DD + col];
      #pragma unroll
      for (int r=0;r<4;r++){
        int g0 = r0 + hq*4 + r;
        if (g0 < M){
          float nn = tanhf(xa0[r] + bin + rr0[r]*(ha0[r] + bhn));
          hW[(size_t)g0*DD + col] = f2b((1.f - zz0[r])*nn + zz0[r]*hp0[r]);
        }
        int g1 = r0 + 16 + hq*4 + r;
        if (g1 < M){
          float nn = tanhf(xa1[r] + bin + rr1[r]*(ha1[r] + bhn));
          hW[(size_t)g1*DD + col] = f2b((1.f - zz1[r])*nn + zz1[r]*hp1[r]);
        }
      }
    }
    // no trailing barrier: the next ds_write targets the OTHER buffer, whose
    // readers finished before the barrier above (publish(sp+2) is 2 barriers away).
  }
}

// ---------------- per-graph mean readout ----------------
__global__ __launch_bounds__(256) void k_batchsum(
    const unsigned short* __restrict__ v_emb, const int* __restrict__ vb,
    float* __restrict__ g_sum, float* __restrict__ g_cnt)
{
  int c = threadIdx.x & (DD-1);
  int half = threadIdx.x >> 7;
  int rs = blockIdx.x*128 + half*64;
  if (rs >= VN) return;
  int re = rs + 64; if (re > VN) re = VN;
  float acc = 0.f, cnt = 0.f;
  int cur = vb[rs];
  for (int r = rs; r < re; r++){
    int b = vb[r];
    if (b != cur){
      atomicAdd(&g_sum[cur*DD + c], acc);
      if (c == 0) atomicAdd(&g_cnt[cur], cnt);
      acc = 0.f; cnt = 0.f; cur = b;
    }
    acc += b2f(v_emb[(size_t)r*DD + c]);
    cnt += 1.f;
  }
  atomicAdd(&g_sum[cur*DD + c], acc);
  if (c == 0) atomicAdd(&g_cnt[cur], cnt);
}

__global__ __launch_bounds__(128) void k_readout(
    const float* __restrict__ g_sum, const float* __restrict__ g_cnt,
    const float* __restrict__ W1, const float* __restrict__ b1,
    const float* __restrict__ W2, const float* __restrict__ b2,
    float* __restrict__ out)
{
  __shared__ float sg[DD];
  __shared__ float sr[DD];
  int b = blockIdx.x, c = threadIdx.x;
  float rc = 1.0f / fmaxf(g_cnt[b], 1.0f);
  sg[c] = g_sum[b*DD + c] * rc;
  __syncthreads();
  float a = b1[c];
  for (int k=0;k<DD;k++) a = fmaf(sg[k], W1[(size_t)k*DD + c], a);
  a = fmaxf(a, 0.f);
  sr[c] = a * W2[c];
  __syncthreads();
  for (int s=64; s>0; s>>=1){
    if (c < s) sr[c] += sr[c+s];
    __syncthreads();
  }
  if (c == 0) out[b] = sigm(sr[0] + b2[0]);
}

// ---------------- orchestration ----------------
extern "C" void kernel_launch(void* const* d_in, const int* in_sizes, int n_in,
                              void* d_out, int out_size, void* d_ws, size_t ws_size,
                              hipStream_t stream)
{
  const int* vE = (const int*)d_in[0];
  const int* cE = (const int*)d_in[1];
  const int* pE = (const int*)d_in[2];
  const int* nE = (const int*)d_in[3];
  const int* vb = (const int*)d_in[4];
  const float* v_init = (const float*)d_in[5];
  const float* c_init = (const float*)d_in[6];
  const float* mW1[4]; const float* mb1[4]; const float* mW2[4]; const float* mb2[4];
  for (int m=0;m<4;m++){
    mW1[m] = (const float*)d_in[7 + m*4 + 0];
    mb1[m] = (const float*)d_in[7 + m*4 + 1];
    mW2[m] = (const float*)d_in[7 + m*4 + 2];
    mb2[m] = (const float*)d_in[7 + m*4 + 3];
  }
  const float* gc_Wih = (const float*)d_in[23];
  const float* gc_Whh = (const float*)d_in[24];
  const float* gc_bih = (const float*)d_in[25];
  const float* gc_bhh = (const float*)d_in[26];
  const float* gv_Wih = (const float*)d_in[27];
  const float* gv_Whh = (const float*)d_in[28];
  const float* gv_bih = (const float*)d_in[29];
  const float* gv_bhh = (const float*)d_in[30];
  const float* ro_W1 = (const float*)d_in[31];
  const float* ro_b1 = (const float*)d_in[32];
  const float* ro_W2 = (const float*)d_in[33];
  const float* ro_b2 = (const float*)d_in[34];
  float* out = (float*)d_out;

  char* base = (char*)d_ws;
  size_t off = 0;
  auto alloc = [&](size_t n)->void*{ void* p = base + off; off += (n + 255) & ~(size_t)255; return p; };
  int* cnt4    = (int*)alloc((size_t)SCN*4);
  int* fill4   = (int*)alloc((size_t)SCN*4);
  int* starts  = (int*)alloc(((size_t)SCN+1)*4);
  int* bsum    = (int*)alloc(512*4);
  int* boff    = (int*)alloc(512*4);
  int* p_v     = (int*)alloc((size_t)EPN*4);
  int* p_c     = (int*)alloc((size_t)EPN*4);
  int* n_v     = (int*)alloc((size_t)ENN*4);
  int* n_c     = (int*)alloc((size_t)ENN*4);
  int* listBuf = (int*)alloc((size_t)2*(EPN+ENN)*4);
  float* rdeg4 = (float*)alloc((size_t)SCN*4);
  unsigned short* v_embA = (unsigned short*)alloc((size_t)VN*DD*2);
  unsigned short* v_embB = (unsigned short*)alloc((size_t)VN*DD*2);
  unsigned short* c_embA = (unsigned short*)alloc((size_t)CN*DD*2);
  unsigned short* c_embB = (unsigned short*)alloc((size_t)CN*DD*2);
  unsigned short* Hp = (unsigned short*)alloc((size_t)CN*DD*2);
  unsigned short* Hn = (unsigned short*)alloc((size_t)CN*DD*2);
  unsigned short* Xg = (unsigned short*)alloc((size_t)CN*2*DD*2);
  unsigned short* P_W1[4]; unsigned short* P_W2[4];
  for (int m=0;m<4;m++){
    P_W1[m] = (unsigned short*)alloc((size_t)DD*DD*2);
    P_W2[m] = (unsigned short*)alloc((size_t)DD*DD*2);
  }
  unsigned short* P_gc = (unsigned short*)alloc((size_t)8*18432*2);
  unsigned short* P_gv = (unsigned short*)alloc((size_t)8*18432*2);
  float* g_sum = (float*)alloc((size_t)BN*DD*4);
  float* g_cnt = (float*)alloc((size_t)BN*4);
  (void)in_sizes; (void)n_in; (void)out_size; (void)ws_size;

  hipMemsetAsync(cnt4, 0, (size_t)SCN*4, stream);
  hipMemsetAsync(fill4, 0, (size_t)SCN*4, stream);

  k_edges<<<(EPN+255)/256, 256, 0, stream>>>(vE, cE, pE, nE, p_v, p_c, n_v, n_c, cnt4);
  k_scan1<<<SC_NB, 256, 0, stream>>>(cnt4, starts, bsum);
  k_scan2<<<1, 512, 0, stream>>>(bsum, boff, starts + SCN);
  k_scan3<<<SC_NB, 256, 0, stream>>>(starts, boff);
  k_fill<<<(EPN+255)/256, 256, 0, stream>>>(p_v, p_c, n_v, n_c, starts, fill4, listBuf);
  k_rdeg<<<(SCN+255)/256, 256, 0, stream>>>(cnt4, rdeg4);

  for (int m=0;m<4;m++){
    k_pack<<<(DD*DD+255)/256, 256, 0, stream>>>(mW1[m], P_W1[m], DD, DD);
    k_pack<<<(DD*DD+255)/256, 256, 0, stream>>>(mW2[m], P_W2[m], DD, DD);
  }
  k_packgru<<<(8*18432+255)/256, 256, 0, stream>>>(gc_Wih, gc_Whh, P_gc);
  k_packgru<<<(8*18432+255)/256, 256, 0, stream>>>(gv_Wih, gv_Whh, P_gv);

  k_init<<<((size_t)VN*DD+255)/256, 256, 0, stream>>>(v_init, v_embA, VN*DD);
  k_init<<<((size_t)CN*DD+255)/256, 256, 0, stream>>>(c_init, c_embA, CN*DD);

  int mlpVb = (VN+127)/128, mlpCb = (CN+127)/128;
  int gruVb = (VN+127)/128, gruCb = (CN+127)/128;
  unsigned short* vc = v_embA; unsigned short* va = v_embB;
  unsigned short* cc = c_embA; unsigned short* ca = c_embB;
  for (int it=0; it<3; ++it){
    // ---- v -> c ----
    k_mlp2dual<<<mlpVb, 256, 0, stream>>>(vc, P_W1[0], mb1[0], P_W2[0], mb2[0],
                                                   P_W1[1], mb1[1], P_W2[1], mb2[1], Hp, Hn, VN);
    k_aggr<<<(CN+15)/16, 256, 0, stream>>>(Hp, Hn, starts, rdeg4, listBuf, Xg, 2*VN, 2*VN+CN, CN);
    k_gru<<<gruCb, 256, 0, stream>>>(cc, ca, Xg, P_gc, gc_bih, gc_bhh, CN);
    { unsigned short* tmp = cc; cc = ca; ca = tmp; }
    // ---- c -> v ----
    k_mlp2dual<<<mlpCb, 256, 0, stream>>>(cc, P_W1[2], mb1[2], P_W2[2], mb2[2],
                                                   P_W1[3], mb1[3], P_W2[3], mb2[3], Hp, Hn, CN);
    k_aggr<<<(VN+15)/16, 256, 0, stream>>>(Hp, Hn, starts, rdeg4, listBuf, Xg, 0, VN, VN);
    k_gru<<<gruVb, 256, 0, stream>>>(vc, va, Xg, P_gv, gv_bih, gv_bhh, VN);
    { unsigned short* tmp = vc; vc = va; va = tmp; }
  }

  hipMemsetAsync(g_sum, 0, (size_t)BN*DD*4, stream);
  hipMemsetAsync(g_cnt, 0, (size_t)BN*4, stream);
  k_batchsum<<<(VN+127)/128, 256, 0, stream>>>(vc, vb, g_sum, g_cnt);
  k_readout<<<BN, 128, 0, stream>>>(g_sum, g_cnt, ro_W1, ro_b1, ro_W2, ro_b2, out);
}

// Round 15
// 881.834 us; speedup vs baseline: 1.0990x; 1.0911x over previous
//
#include <hip/hip_runtime.h>

#define VN 30000
#define CN 120000
#define EPN 180000
#define ENN 180000
#define DD 128
#define BN 32
#define SCN (2*VN + 2*CN)          // 300000 concatenated degree rows: PV | NV | PC | NC
#define SC_NB ((SCN + 1023) / 1024) // 293 scan blocks

using bf16x8 = __attribute__((ext_vector_type(8))) short;
using f32x4  = __attribute__((ext_vector_type(4))) float;

static __device__ __forceinline__ float frcp(float x){ return __builtin_amdgcn_rcpf(x); }
static __device__ __forceinline__ float sigm(float x){ return frcp(1.0f + __expf(-x)); }
static __device__ __forceinline__ float ftanh(float x){
  float t = __expf(2.0f*x);
  return (t - 1.0f) * frcp(t + 1.0f);
}
static __device__ __forceinline__ unsigned short f2b(float f){
  unsigned int u = __float_as_uint(f);
  unsigned int r = u + 0x7fffu + ((u>>16)&1u);
  return (unsigned short)(r>>16);
}
static __device__ __forceinline__ float b2f(unsigned short s){
  return __uint_as_float(((unsigned int)s)<<16);
}

// ---------------- edge endpoints + integer degree counts ----------------
__global__ __launch_bounds__(256) void k_edges(
    const int* __restrict__ vE, const int* __restrict__ cE,
    const int* __restrict__ pE, const int* __restrict__ nE,
    int* __restrict__ p_v, int* __restrict__ p_c,
    int* __restrict__ n_v, int* __restrict__ n_c,
    int* __restrict__ cnt)
{
  int i = blockIdx.x*256 + threadIdx.x;
  if (i < EPN){
    int e = pE[i]; int v = vE[e], c = cE[e];
    p_v[i] = v; p_c[i] = c;
    atomicAdd(&cnt[v], 1); atomicAdd(&cnt[2*VN + c], 1);
  }
  if (i < ENN){
    int e = nE[i]; int v = vE[e], c = cE[e];
    n_v[i] = v; n_c[i] = c;
    atomicAdd(&cnt[VN + v], 1); atomicAdd(&cnt[2*VN + CN + c], 1);
  }
}

// ---------------- 3-phase exclusive scan over cnt[SCN] ----------------
__global__ __launch_bounds__(256) void k_scan1(const int* __restrict__ cnt, int* __restrict__ part, int* __restrict__ bsum){
  __shared__ int s[256];
  int b = blockIdx.x, t = threadIdx.x;
  int base = b*1024 + t*4;
  int v0 = (base+0<SCN)?cnt[base+0]:0;
  int v1 = (base+1<SCN)?cnt[base+1]:0;
  int v2 = (base+2<SCN)?cnt[base+2]:0;
  int v3 = (base+3<SCN)?cnt[base+3]:0;
  int loc = v0+v1+v2+v3;
  s[t] = loc; __syncthreads();
  for (int off=1; off<256; off<<=1){
    int x = (t>=off)? s[t-off] : 0;
    __syncthreads();
    s[t] += x;
    __syncthreads();
  }
  int excl = s[t]-loc;
  if (t==255) bsum[b] = s[255];
  if (base  <SCN) part[base  ] = excl;
  if (base+1<SCN) part[base+1] = excl+v0;
  if (base+2<SCN) part[base+2] = excl+v0+v1;
  if (base+3<SCN) part[base+3] = excl+v0+v1+v2;
}
__global__ __launch_bounds__(512) void k_scan2(const int* __restrict__ bsum, int* __restrict__ boff, int* __restrict__ total_out){
  __shared__ int s[512];
  int t = threadIdx.x;
  int v = (t<SC_NB)? bsum[t] : 0;
  s[t]=v; __syncthreads();
  for (int off=1; off<512; off<<=1){
    int x = (t>=off)? s[t-off] : 0;
    __syncthreads();
    s[t]+=x;
    __syncthreads();
  }
  if (t<SC_NB) boff[t] = s[t]-v;
  if (t==511) total_out[0] = s[511];
}
__global__ __launch_bounds__(256) void k_scan3(int* __restrict__ part, const int* __restrict__ boff){
  int b = blockIdx.x; int base = b*1024 + threadIdx.x*4; int o = boff[b];
  #pragma unroll
  for (int i=0;i<4;i++) if (base+i < SCN) part[base+i] += o;
}

// ---------------- CSR bucket fill ----------------
__global__ __launch_bounds__(256) void k_fill(
    const int* __restrict__ p_v, const int* __restrict__ p_c,
    const int* __restrict__ n_v, const int* __restrict__ n_c,
    const int* __restrict__ starts, int* __restrict__ fill, int* __restrict__ listBuf)
{
  int i = blockIdx.x*256 + threadIdx.x;
  if (i < EPN){
    int v = p_v[i], c = p_c[i];
    int s1 = starts[v]        + atomicAdd(&fill[v], 1);          listBuf[s1] = c; // PV
    int s2 = starts[2*VN + c] + atomicAdd(&fill[2*VN + c], 1);   listBuf[s2] = v; // PC
  }
  if (i < ENN){
    int v = n_v[i], c = n_c[i];
    int s1 = starts[VN + v]        + atomicAdd(&fill[VN + v], 1);        listBuf[s1] = c; // NV
    int s2 = starts[2*VN + CN + c] + atomicAdd(&fill[2*VN + CN + c], 1); listBuf[s2] = v; // NC
  }
}

__global__ __launch_bounds__(256) void k_rdeg(const int* __restrict__ cnt, float* __restrict__ rdeg){
  int i = blockIdx.x*256 + threadIdx.x;
  if (i < SCN) rdeg[i] = 1.0f / (float)max(cnt[i], 1);
}

// ---------------- weight packing: W[K][N] f32 -> fragment-major bf16 ----------------
__global__ __launch_bounds__(256) void k_pack(const float* __restrict__ W, unsigned short* __restrict__ Wp, int K, int N){
  int o = blockIdx.x*256 + threadIdx.x;
  if (o >= K*N) return;
  int j = o & 7, l = (o>>3) & 63, frag = o >> 9;
  int K32 = K >> 5;
  int n0 = frag / K32, k0 = frag - n0*K32;
  int k = k0*32 + (l>>4)*8 + j, n = n0*16 + (l&15);
  Wp[o] = f2b(W[(size_t)k*N + n]);
}

// ---------------- GRU weight packing: per-(col-tile,gate) contiguous 12KB blocks ----------------
__global__ __launch_bounds__(256) void k_packgru(
    const float* __restrict__ Wih, const float* __restrict__ Whh,
    unsigned short* __restrict__ Wg)
{
  int idx = blockIdx.x*256 + threadIdx.x;
  if (idx >= 8*18432) return;
  int n0l = idx / 18432;
  int r = idx - n0l*18432;
  int g = r / 6144;
  int r2 = r - g*6144;
  int ih = (r2 < 4096) ? 1 : 0;
  int r3 = ih ? r2 : r2 - 4096;
  int k0 = r3 >> 9;
  int e = r3 & 511;
  int l = e >> 3, j = e & 7;
  int k = k0*32 + (l>>4)*8 + j;
  int n = g*128 + n0l*16 + (l&15);
  float v = ih ? Wih[(size_t)k*384 + n] : Whh[(size_t)k*384 + n];
  Wg[idx] = f2b(v);
}

__global__ __launch_bounds__(256) void k_init(const float* __restrict__ ini, unsigned short* __restrict__ emb, int total){
  int i = blockIdx.x*256 + threadIdx.x;
  if (i < total) emb[i] = f2b(ini[i & (DD-1)] * 0.08838834764831845f); // 1/sqrt(128)
}

// ---------------- dual two-layer MLP: 32 rows/wave, 8KB LDS/wave, bf16 X ----------------
__global__ __launch_bounds__(256) void k_mlp2dual(
    const unsigned short* __restrict__ X,
    const unsigned short* __restrict__ W1p, const float* __restrict__ b1p,
    const unsigned short* __restrict__ W2p, const float* __restrict__ b2p,
    const unsigned short* __restrict__ W1n, const float* __restrict__ b1n,
    const unsigned short* __restrict__ W2n, const float* __restrict__ b2n,
    unsigned short* __restrict__ Hp, unsigned short* __restrict__ Hn, int M)
{
  __shared__ __align__(16) char smem[32768];
  int t = threadIdx.x, lane = t & 63, wid = t >> 6;
  int r0 = blockIdx.x*128 + wid*32;
  if (r0 >= M) return;  // per-wave LDS only; no block barriers
  char* sW = smem + wid*8192;   // [32][128] bf16 swizzled; reused X -> H1 -> out
  int row16 = lane & 15, hq = lane >> 4, col0 = row16;

  // stage 32 rows of X (bf16, coalesced uint4) -> swizzled
  #pragma unroll
  for (int q=0;q<8;q++){
    int i = q*64 + lane; int row = i >> 4, cb = i & 15;
    int gr = r0 + row; if (gr >= M) gr = M-1;
    uint4 u = *(const uint4*)&X[(size_t)gr*DD + cb*8];
    *(uint4*)&sW[row*256 + ((cb^(row&7))<<4)] = u;
  }
  bf16x8 aX[2][4];
  #pragma unroll
  for (int tt=0;tt<2;tt++){
    int rowl = tt*16 + row16;
    #pragma unroll
    for (int k0=0;k0<4;k0++)
      aX[tt][k0] = *(const bf16x8*)&sW[rowl*256 + (((k0*4+hq)^(rowl&7))<<4)];
  }
  #pragma unroll
  for (int pn=0; pn<2; pn++){
    const unsigned short* W1 = pn? W1n : W1p; const float* b1 = pn? b1n : b1p;
    const unsigned short* W2 = pn? W2n : W2p; const float* b2 = pn? b2n : b2p;
    unsigned short* Hout = pn? Hn : Hp;
    // ---- layer 1: relu(X@W1+b1) -> sW ----
    bf16x8 wn[4];
    #pragma unroll
    for (int k0=0;k0<4;k0++) wn[k0] = *(const bf16x8*)&W1[((size_t)k0*64+lane)*8];
    #pragma unroll
    for (int n0=0;n0<8;n0++){
      bf16x8 wc[4];
      #pragma unroll
      for (int k0=0;k0<4;k0++) wc[k0] = wn[k0];
      if (n0 < 7){
        #pragma unroll
        for (int k0=0;k0<4;k0++) wn[k0] = *(const bf16x8*)&W1[((size_t)((n0+1)*4+k0)*64+lane)*8];
      }
      f32x4 acc[2] = {{0,0,0,0},{0,0,0,0}};
      #pragma unroll
      for (int k0=0;k0<4;k0++)
        #pragma unroll
        for (int tt=0;tt<2;tt++)
          acc[tt] = __builtin_amdgcn_mfma_f32_16x16x32_bf16(aX[tt][k0], wc[k0], acc[tt], 0,0,0);
      int col = n0*16 + col0;
      float bb = b1[col];
      #pragma unroll
      for (int tt=0;tt<2;tt++)
        #pragma unroll
        for (int r=0;r<4;r++){
          float v = fmaxf(acc[tt][r]+bb, 0.f);
          int rowl = tt*16 + hq*4 + r;
          *(unsigned short*)&sW[rowl*256 + (((col>>3)^(rowl&7))<<4) + (col&7)*2] = f2b(v);
        }
    }
    // ---- layer 2: H@W2+b2 ----
    bf16x8 aH[2][4];
    #pragma unroll
    for (int tt=0;tt<2;tt++){
      int rowl = tt*16 + row16;
      #pragma unroll
      for (int k0=0;k0<4;k0++)
        aH[tt][k0] = *(const bf16x8*)&sW[rowl*256 + (((k0*4+hq)^(rowl&7))<<4)];
    }
    #pragma unroll
    for (int k0=0;k0<4;k0++) wn[k0] = *(const bf16x8*)&W2[((size_t)k0*64+lane)*8];
    #pragma unroll
    for (int n0=0;n0<8;n0++){
      bf16x8 wc[4];
      #pragma unroll
      for (int k0=0;k0<4;k0++) wc[k0] = wn[k0];
      if (n0 < 7){
        #pragma unroll
        for (int k0=0;k0<4;k0++) wn[k0] = *(const bf16x8*)&W2[((size_t)((n0+1)*4+k0)*64+lane)*8];
      }
      f32x4 acc[2] = {{0,0,0,0},{0,0,0,0}};
      #pragma unroll
      for (int k0=0;k0<4;k0++)
        #pragma unroll
        for (int tt=0;tt<2;tt++)
          acc[tt] = __builtin_amdgcn_mfma_f32_16x16x32_bf16(aH[tt][k0], wc[k0], acc[tt], 0,0,0);
      int col = n0*16 + col0;
      float bb = b2[col];
      #pragma unroll
      for (int tt=0;tt<2;tt++)
        #pragma unroll
        for (int r=0;r<4;r++){
          int rowl = tt*16 + hq*4 + r;
          *(unsigned short*)&sW[rowl*256 + (((col>>3)^(rowl&7))<<4) + (col&7)*2] = f2b(acc[tt][r]+bb);
        }
    }
    // cooperative (within-wave) coalesced store of 32 rows
    #pragma unroll
    for (int q=0;q<8;q++){
      int i = lane + q*64; int rowl = i>>4, cb = i&15;
      int grow = r0 + rowl;
      if (grow < M)
        *(uint4*)&Hout[(size_t)grow*DD + cb*8] = *(const uint4*)&sW[rowl*256 + ((cb^(rowl&7))<<4)];
    }
  }
}

// ---------------- CSR gather-mean aggregation: 16 lanes/dest, interleaved p/n chains ----------------
__global__ __launch_bounds__(256) void k_aggr(
    const unsigned short* __restrict__ Hp, const unsigned short* __restrict__ Hn,
    const int* __restrict__ starts, const float* __restrict__ rdeg, const int* __restrict__ listBuf,
    unsigned short* __restrict__ Xg, int baseP, int baseN, int M)
{
  int d = blockIdx.x*16 + (threadIdx.x >> 4);
  if (d >= M) return;
  int l16 = threadIdx.x & 15;
  int qp = starts[baseP + d], ep = starts[baseP + d + 1];
  int qn = starts[baseN + d], en = starts[baseN + d + 1];
  float ap[8], an[8];
  #pragma unroll
  for (int j=0;j<8;j++){ ap[j]=0.f; an[j]=0.f; }
  while (qp < ep && qn < en){
    int sp_ = listBuf[qp++];
    int sn_ = listBuf[qn++];
    uint4 up = *(const uint4*)&Hp[(size_t)sp_*DD + l16*8];
    uint4 un = *(const uint4*)&Hn[(size_t)sn_*DD + l16*8];
    ap[0]+=b2f((unsigned short)up.x); ap[1]+=b2f((unsigned short)(up.x>>16));
    ap[2]+=b2f((unsigned short)up.y); ap[3]+=b2f((unsigned short)(up.y>>16));
    ap[4]+=b2f((unsigned short)up.z); ap[5]+=b2f((unsigned short)(up.z>>16));
    ap[6]+=b2f((unsigned short)up.w); ap[7]+=b2f((unsigned short)(up.w>>16));
    an[0]+=b2f((unsigned short)un.x); an[1]+=b2f((unsigned short)(un.x>>16));
    an[2]+=b2f((unsigned short)un.y); an[3]+=b2f((unsigned short)(un.y>>16));
    an[4]+=b2f((unsigned short)un.z); an[5]+=b2f((unsigned short)(un.z>>16));
    an[6]+=b2f((unsigned short)un.w); an[7]+=b2f((unsigned short)(un.w>>16));
  }
  while (qp < ep){
    int src = listBuf[qp++];
    uint4 u = *(const uint4*)&Hp[(size_t)src*DD + l16*8];
    ap[0]+=b2f((unsigned short)u.x); ap[1]+=b2f((unsigned short)(u.x>>16));
    ap[2]+=b2f((unsigned short)u.y); ap[3]+=b2f((unsigned short)(u.y>>16));
    ap[4]+=b2f((unsigned short)u.z); ap[5]+=b2f((unsigned short)(u.z>>16));
    ap[6]+=b2f((unsigned short)u.w); ap[7]+=b2f((unsigned short)(u.w>>16));
  }
  while (qn < en){
    int src = listBuf[qn++];
    uint4 u = *(const uint4*)&Hn[(size_t)src*DD + l16*8];
    an[0]+=b2f((unsigned short)u.x); an[1]+=b2f((unsigned short)(u.x>>16));
    an[2]+=b2f((unsigned short)u.y); an[3]+=b2f((unsigned short)(u.y>>16));
    an[4]+=b2f((unsigned short)u.z); an[5]+=b2f((unsigned short)(u.z>>16));
    an[6]+=b2f((unsigned short)u.w); an[7]+=b2f((unsigned short)(u.w>>16));
  }
  float rp = rdeg[baseP + d];
  float rn = rdeg[baseN + d];
  uint4 o;
  o.x = (unsigned)f2b(ap[0]*rp) | ((unsigned)f2b(ap[1]*rp)<<16);
  o.y = (unsigned)f2b(ap[2]*rp) | ((unsigned)f2b(ap[3]*rp)<<16);
  o.z = (unsigned)f2b(ap[4]*rp) | ((unsigned)f2b(ap[5]*rp)<<16);
  o.w = (unsigned)f2b(ap[6]*rp) | ((unsigned)f2b(ap[7]*rp)<<16);
  *(uint4*)&Xg[(size_t)d*(2*DD) + l16*8] = o;
  o.x = (unsigned)f2b(an[0]*rn) | ((unsigned)f2b(an[1]*rn)<<16);
  o.y = (unsigned)f2b(an[2]*rn) | ((unsigned)f2b(an[3]*rn)<<16);
  o.z = (unsigned)f2b(an[4]*rn) | ((unsigned)f2b(an[5]*rn)<<16);
  o.w = (unsigned)f2b(an[6]*rn) | ((unsigned)f2b(an[7]*rn)<<16);
  *(uint4*)&Xg[(size_t)d*(2*DD) + DD + l16*8] = o;
}

// ---------------- fused GRU: reg-staged 1-deep weight pipeline, bf16 h, fast transcendentals ----------------
// 4 waves x 32 rows = 128 rows/block. 24 sub-phases (col-tile x gate), 12KB weights each.
// Per sub-phase: ds_write staged regs -> barrier -> issue next loads -> compute.
__global__ __launch_bounds__(256) void k_gru(
    const unsigned short* __restrict__ hR, unsigned short* __restrict__ hW,
    const unsigned short* __restrict__ Xg,
    const unsigned short* __restrict__ Wg,
    const float* __restrict__ bih, const float* __restrict__ bhh,
    int M)
{
  __shared__ __align__(16) char sW[2][12288];
  int t = threadIdx.x, lane = t & 63;
  int wid = t >> 6;
  int r0 = blockIdx.x*128 + wid*32;
  int row16 = lane & 15, hq = lane >> 4, col0 = row16;
  int kb = hq*8;
  // A fragments (rows clamped; no early return — barriers below)
  bf16x8 aX[2][8];
  bf16x8 aH[2][4];
  #pragma unroll
  for (int tt=0;tt<2;tt++){
    int row = r0 + tt*16 + row16; if (row >= M) row = M-1;
    const unsigned short* xp = &Xg[(size_t)row*(2*DD) + kb];
    #pragma unroll
    for (int k0=0;k0<8;k0++) aX[tt][k0] = *(const bf16x8*)(xp + k0*32);
    const unsigned short* hp = &hR[(size_t)row*DD + kb];
    #pragma unroll
    for (int k0=0;k0<4;k0++) aH[tt][k0] = *(const bf16x8*)(hp + k0*32);
  }
  // reg-staged weight pipeline: each thread owns 3x16B slices of the 12KB sub-block
  int s0 = wid*3;
  const char* wsrc = (const char*)Wg + (size_t)s0*1024 + lane*16;
  char* d0 = &sW[0][(size_t)s0*1024 + lane*16];
  char* d1 = &sW[1][(size_t)s0*1024 + lane*16];
  uint4 wr0 = *(const uint4*)(wsrc);
  uint4 wr1 = *(const uint4*)(wsrc + 1024);
  uint4 wr2 = *(const uint4*)(wsrc + 2048);
  f32x4 rr0, rr1, zz0, zz1, hp0, hp1;
  #pragma unroll 1
  for (int sp = 0; sp < 24; sp++){
    int cur = sp & 1;
    // publish this sub-phase's weights (loaded last iteration / prologue)
    char* dst = cur ? d1 : d0;
    *(uint4*)(dst)        = wr0;
    *(uint4*)(dst + 1024) = wr1;
    *(uint4*)(dst + 2048) = wr2;
    __syncthreads();
    // issue next sub-phase's loads AFTER the barrier: full compute phase of slack
    if (sp < 23){
      const char* src = wsrc + (size_t)(sp+1)*12288;
      wr0 = *(const uint4*)(src);
      wr1 = *(const uint4*)(src + 1024);
      wr2 = *(const uint4*)(src + 2048);
    }
    int n0l = sp / 3;
    int gate = sp - n0l*3;
    int col = n0l*16 + col0;
    const char* wb = &sW[cur][0] + lane*16;
    // X-part and H-part accumulated separately (N gate needs them split)
    f32x4 xa0 = {0,0,0,0}, xa1 = {0,0,0,0};
    f32x4 ha0 = {0,0,0,0}, ha1 = {0,0,0,0};
    #pragma unroll
    for (int k0=0;k0<8;k0++){
      bf16x8 w = *(const bf16x8*)(wb + k0*1024);
      xa0 = __builtin_amdgcn_mfma_f32_16x16x32_bf16(aX[0][k0], w, xa0, 0,0,0);
      xa1 = __builtin_amdgcn_mfma_f32_16x16x32_bf16(aX[1][k0], w, xa1, 0,0,0);
    }
    #pragma unroll
    for (int k0=0;k0<4;k0++){
      bf16x8 w = *(const bf16x8*)(wb + 8192 + k0*1024);
      ha0 = __builtin_amdgcn_mfma_f32_16x16x32_bf16(aH[0][k0], w, ha0, 0,0,0);
      ha1 = __builtin_amdgcn_mfma_f32_16x16x32_bf16(aH[1][k0], w, ha1, 0,0,0);
    }
    if (gate == 0){
      float br = bih[col] + bhh[col];
      #pragma unroll
      for (int r=0;r<4;r++){
        rr0[r] = sigm(xa0[r] + ha0[r] + br);
        rr1[r] = sigm(xa1[r] + ha1[r] + br);
      }
      // prefetch old-h epilogue values (ready 2 sub-phases later at the N gate)
      #pragma unroll
      for (int r=0;r<4;r++){
        int g0 = r0 + hq*4 + r;      if (g0 >= M) g0 = M-1;
        int g1 = r0 + 16 + hq*4 + r; if (g1 >= M) g1 = M-1;
        hp0[r] = b2f(hR[(size_t)g0*DD + col]);
        hp1[r] = b2f(hR[(size_t)g1*DD + col]);
      }
    } else if (gate == 1){
      float bz = bih[DD + col] + bhh[DD + col];
      #pragma unroll
      for (int r=0;r<4;r++){
        zz0[r] = sigm(xa0[r] + ha0[r] + bz);
        zz1[r] = sigm(xa1[r] + ha1[r] + bz);
      }
    } else {
      float bin = bih[2*DD + col], bhn = bhh[2*DD + col];
      #pragma unroll
      for (int r=0;r<4;r++){
        int g0 = r0 + hq*4 + r;
        if (g0 < M){
          float nn = ftanh(xa0[r] + bin + rr0[r]*(ha0[r] + bhn));
          hW[(size_t)g0*DD + col] = f2b((1.f - zz0[r])*nn + zz0[r]*hp0[r]);
        }
        int g1 = r0 + 16 + hq*4 + r;
        if (g1 < M){
          float nn = ftanh(xa1[r] + bin + rr1[r]*(ha1[r] + bhn));
          hW[(size_t)g1*DD + col] = f2b((1.f - zz1[r])*nn + zz1[r]*hp1[r]);
        }
      }
    }
    // no trailing barrier needed: next ds_write targets the OTHER buffer,
    // whose last readers finished before the barrier above.
  }
}

// ---------------- per-graph mean readout ----------------
__global__ __launch_bounds__(256) void k_batchsum(
    const unsigned short* __restrict__ v_emb, const int* __restrict__ vb,
    float* __restrict__ g_sum, float* __restrict__ g_cnt)
{
  int c = threadIdx.x & (DD-1);
  int half = threadIdx.x >> 7;
  int rs = blockIdx.x*128 + half*64;
  if (rs >= VN) return;
  int re = rs + 64; if (re > VN) re = VN;
  float acc = 0.f, cnt = 0.f;
  int cur = vb[rs];
  for (int r = rs; r < re; r++){
    int b = vb[r];
    if (b != cur){
      atomicAdd(&g_sum[cur*DD + c], acc);
      if (c == 0) atomicAdd(&g_cnt[cur], cnt);
      acc = 0.f; cnt = 0.f; cur = b;
    }
    acc += b2f(v_emb[(size_t)r*DD + c]);
    cnt += 1.f;
  }
  atomicAdd(&g_sum[cur*DD + c], acc);
  if (c == 0) atomicAdd(&g_cnt[cur], cnt);
}

__global__ __launch_bounds__(128) void k_readout(
    const float* __restrict__ g_sum, const float* __restrict__ g_cnt,
    const float* __restrict__ W1, const float* __restrict__ b1,
    const float* __restrict__ W2, const float* __restrict__ b2,
    float* __restrict__ out)
{
  __shared__ float sg[DD];
  __shared__ float sr[DD];
  int b = blockIdx.x, c = threadIdx.x;
  float rc = 1.0f / fmaxf(g_cnt[b], 1.0f);
  sg[c] = g_sum[b*DD + c] * rc;
  __syncthreads();
  float a = b1[c];
  for (int k=0;k<DD;k++) a = fmaf(sg[k], W1[(size_t)k*DD + c], a);
  a = fmaxf(a, 0.f);
  sr[c] = a * W2[c];
  __syncthreads();
  for (int s=64; s>0; s>>=1){
    if (c < s) sr[c] += sr[c+s];
    __syncthreads();
  }
  if (c == 0) out[b] = sigm(sr[0] + b2[0]);
}

// ---------------- orchestration ----------------
extern "C" void kernel_launch(void* const* d_in, const int* in_sizes, int n_in,
                              void* d_out, int out_size, void* d_ws, size_t ws_size,
                              hipStream_t stream)
{
  const int* vE = (const int*)d_in[0];
  const int* cE = (const int*)d_in[1];
  const int* pE = (const int*)d_in[2];
  const int* nE = (const int*)d_in[3];
  const int* vb = (const int*)d_in[4];
  const float* v_init = (const float*)d_in[5];
  const float* c_init = (const float*)d_in[6];
  const float* mW1[4]; const float* mb1[4]; const float* mW2[4]; const float* mb2[4];
  for (int m=0;m<4;m++){
    mW1[m] = (const float*)d_in[7 + m*4 + 0];
    mb1[m] = (const float*)d_in[7 + m*4 + 1];
    mW2[m] = (const float*)d_in[7 + m*4 + 2];
    mb2[m] = (const float*)d_in[7 + m*4 + 3];
  }
  const float* gc_Wih = (const float*)d_in[23];
  const float* gc_Whh = (const float*)d_in[24];
  const float* gc_bih = (const float*)d_in[25];
  const float* gc_bhh = (const float*)d_in[26];
  const float* gv_Wih = (const float*)d_in[27];
  const float* gv_Whh = (const float*)d_in[28];
  const float* gv_bih = (const float*)d_in[29];
  const float* gv_bhh = (const float*)d_in[30];
  const float* ro_W1 = (const float*)d_in[31];
  const float* ro_b1 = (const float*)d_in[32];
  const float* ro_W2 = (const float*)d_in[33];
  const float* ro_b2 = (const float*)d_in[34];
  float* out = (float*)d_out;

  char* base = (char*)d_ws;
  size_t off = 0;
  auto alloc = [&](size_t n)->void*{ void* p = base + off; off += (n + 255) & ~(size_t)255; return p; };
  int* cnt4    = (int*)alloc((size_t)SCN*4);
  int* fill4   = (int*)alloc((size_t)SCN*4);
  int* starts  = (int*)alloc(((size_t)SCN+1)*4);
  int* bsum    = (int*)alloc(512*4);
  int* boff    = (int*)alloc(512*4);
  int* p_v     = (int*)alloc((size_t)EPN*4);
  int* p_c     = (int*)alloc((size_t)EPN*4);
  int* n_v     = (int*)alloc((size_t)ENN*4);
  int* n_c     = (int*)alloc((size_t)ENN*4);
  int* listBuf = (int*)alloc((size_t)2*(EPN+ENN)*4);
  float* rdeg4 = (float*)alloc((size_t)SCN*4);
  unsigned short* v_embA = (unsigned short*)alloc((size_t)VN*DD*2);
  unsigned short* v_embB = (unsigned short*)alloc((size_t)VN*DD*2);
  unsigned short* c_embA = (unsigned short*)alloc((size_t)CN*DD*2);
  unsigned short* c_embB = (unsigned short*)alloc((size_t)CN*DD*2);
  unsigned short* Hp = (unsigned short*)alloc((size_t)CN*DD*2);
  unsigned short* Hn = (unsigned short*)alloc((size_t)CN*DD*2);
  unsigned short* Xg = (unsigned short*)alloc((size_t)CN*2*DD*2);
  unsigned short* P_W1[4]; unsigned short* P_W2[4];
  for (int m=0;m<4;m++){
    P_W1[m] = (unsigned short*)alloc((size_t)DD*DD*2);
    P_W2[m] = (unsigned short*)alloc((size_t)DD*DD*2);
  }
  unsigned short* P_gc = (unsigned short*)alloc((size_t)8*18432*2);
  unsigned short* P_gv = (unsigned short*)alloc((size_t)8*18432*2);
  float* g_sum = (float*)alloc((size_t)BN*DD*4);
  float* g_cnt = (float*)alloc((size_t)BN*4);
  (void)in_sizes; (void)n_in; (void)out_size; (void)ws_size;

  hipMemsetAsync(cnt4, 0, (size_t)SCN*4, stream);
  hipMemsetAsync(fill4, 0, (size_t)SCN*4, stream);

  k_edges<<<(EPN+255)/256, 256, 0, stream>>>(vE, cE, pE, nE, p_v, p_c, n_v, n_c, cnt4);
  k_scan1<<<SC_NB, 256, 0, stream>>>(cnt4, starts, bsum);
  k_scan2<<<1, 512, 0, stream>>>(bsum, boff, starts + SCN);
  k_scan3<<<SC_NB, 256, 0, stream>>>(starts, boff);
  k_fill<<<(EPN+255)/256, 256, 0, stream>>>(p_v, p_c, n_v, n_c, starts, fill4, listBuf);
  k_rdeg<<<(SCN+255)/256, 256, 0, stream>>>(cnt4, rdeg4);

  for (int m=0;m<4;m++){
    k_pack<<<(DD*DD+255)/256, 256, 0, stream>>>(mW1[m], P_W1[m], DD, DD);
    k_pack<<<(DD*DD+255)/256, 256, 0, stream>>>(mW2[m], P_W2[m], DD, DD);
  }
  k_packgru<<<(8*18432+255)/256, 256, 0, stream>>>(gc_Wih, gc_Whh, P_gc);
  k_packgru<<<(8*18432+255)/256, 256, 0, stream>>>(gv_Wih, gv_Whh, P_gv);

  k_init<<<((size_t)VN*DD+255)/256, 256, 0, stream>>>(v_init, v_embA, VN*DD);
  k_init<<<((size_t)CN*DD+255)/256, 256, 0, stream>>>(c_init, c_embA, CN*DD);

  int mlpVb = (VN+127)/128, mlpCb = (CN+127)/128;
  int gruVb = (VN+127)/128, gruCb = (CN+127)/128;
  unsigned short* vc = v_embA; unsigned short* va = v_embB;
  unsigned short* cc = c_embA; unsigned short* ca = c_embB;
  for (int it=0; it<3; ++it){
    // ---- v -> c ----
    k_mlp2dual<<<mlpVb, 256, 0, stream>>>(vc, P_W1[0], mb1[0], P_W2[0], mb2[0],
                                                   P_W1[1], mb1[1], P_W2[1], mb2[1], Hp, Hn, VN);
    k_aggr<<<(CN+15)/16, 256, 0, stream>>>(Hp, Hn, starts, rdeg4, listBuf, Xg, 2*VN, 2*VN+CN, CN);
    k_gru<<<gruCb, 256, 0, stream>>>(cc, ca, Xg, P_gc, gc_bih, gc_bhh, CN);
    { unsigned short* tmp = cc; cc = ca; ca = tmp; }
    // ---- c -> v ----
    k_mlp2dual<<<mlpCb, 256, 0, stream>>>(cc, P_W1[2], mb1[2], P_W2[2], mb2[2],
                                                   P_W1[3], mb1[3], P_W2[3], mb2[3], Hp, Hn, CN);
    k_aggr<<<(VN+15)/16, 256, 0, stream>>>(Hp, Hn, starts, rdeg4, listBuf, Xg, 0, VN, VN);
    k_gru<<<gruVb, 256, 0, stream>>>(vc, va, Xg, P_gv, gv_bih, gv_bhh, VN);
    { unsigned short* tmp = vc; vc = va; va = tmp; }
  }

  hipMemsetAsync(g_sum, 0, (size_t)BN*DD*4, stream);
  hipMemsetAsync(g_cnt, 0, (size_t)BN*4, stream);
  k_batchsum<<<(VN+127)/128, 256, 0, stream>>>(vc, vb, g_sum, g_cnt);
  k_readout<<<BN, 128, 0, stream>>>(g_sum, g_cnt, ro_W1, ro_b1, ro_W2, ro_b2, out);
}

// Round 16
// 867.439 us; speedup vs baseline: 1.1173x; 1.0166x over previous
//
#include <hip/hip_runtime.h>

#define VN 30000
#define CN 120000
#define EPN 180000
#define ENN 180000
#define DD 128
#define BN 32
#define SCN (2*VN + 2*CN)          // 300000 concatenated degree rows: PV | NV | PC | NC
#define SC_NB ((SCN + 1023) / 1024) // 293 scan blocks

using bf16x8 = __attribute__((ext_vector_type(8))) short;
using f32x4  = __attribute__((ext_vector_type(4))) float;

static __device__ __forceinline__ float frcp(float x){ return __builtin_amdgcn_rcpf(x); }
static __device__ __forceinline__ float sigm(float x){ return frcp(1.0f + __expf(-x)); }
static __device__ __forceinline__ float ftanh(float x){
  float t = __expf(2.0f*x);
  return (t - 1.0f) * frcp(t + 1.0f);
}
static __device__ __forceinline__ unsigned short f2b(float f){
  unsigned int u = __float_as_uint(f);
  unsigned int r = u + 0x7fffu + ((u>>16)&1u);
  return (unsigned short)(r>>16);
}
static __device__ __forceinline__ float b2f(unsigned short s){
  return __uint_as_float(((unsigned int)s)<<16);
}

// ---------------- edge endpoints + integer degree counts ----------------
__global__ __launch_bounds__(256) void k_edges(
    const int* __restrict__ vE, const int* __restrict__ cE,
    const int* __restrict__ pE, const int* __restrict__ nE,
    int* __restrict__ p_v, int* __restrict__ p_c,
    int* __restrict__ n_v, int* __restrict__ n_c,
    int* __restrict__ cnt)
{
  int i = blockIdx.x*256 + threadIdx.x;
  if (i < EPN){
    int e = pE[i]; int v = vE[e], c = cE[e];
    p_v[i] = v; p_c[i] = c;
    atomicAdd(&cnt[v], 1); atomicAdd(&cnt[2*VN + c], 1);
  }
  if (i < ENN){
    int e = nE[i]; int v = vE[e], c = cE[e];
    n_v[i] = v; n_c[i] = c;
    atomicAdd(&cnt[VN + v], 1); atomicAdd(&cnt[2*VN + CN + c], 1);
  }
}

// ---------------- 3-phase exclusive scan over cnt[SCN] ----------------
__global__ __launch_bounds__(256) void k_scan1(const int* __restrict__ cnt, int* __restrict__ part, int* __restrict__ bsum){
  __shared__ int s[256];
  int b = blockIdx.x, t = threadIdx.x;
  int base = b*1024 + t*4;
  int v0 = (base+0<SCN)?cnt[base+0]:0;
  int v1 = (base+1<SCN)?cnt[base+1]:0;
  int v2 = (base+2<SCN)?cnt[base+2]:0;
  int v3 = (base+3<SCN)?cnt[base+3]:0;
  int loc = v0+v1+v2+v3;
  s[t] = loc; __syncthreads();
  for (int off=1; off<256; off<<=1){
    int x = (t>=off)? s[t-off] : 0;
    __syncthreads();
    s[t] += x;
    __syncthreads();
  }
  int excl = s[t]-loc;
  if (t==255) bsum[b] = s[255];
  if (base  <SCN) part[base  ] = excl;
  if (base+1<SCN) part[base+1] = excl+v0;
  if (base+2<SCN) part[base+2] = excl+v0+v1;
  if (base+3<SCN) part[base+3] = excl+v0+v1+v2;
}
__global__ __launch_bounds__(512) void k_scan2(const int* __restrict__ bsum, int* __restrict__ boff, int* __restrict__ total_out){
  __shared__ int s[512];
  int t = threadIdx.x;
  int v = (t<SC_NB)? bsum[t] : 0;
  s[t]=v; __syncthreads();
  for (int off=1; off<512; off<<=1){
    int x = (t>=off)? s[t-off] : 0;
    __syncthreads();
    s[t]+=x;
    __syncthreads();
  }
  if (t<SC_NB) boff[t] = s[t]-v;
  if (t==511) total_out[0] = s[511];
}
__global__ __launch_bounds__(256) void k_scan3(int* __restrict__ part, const int* __restrict__ boff){
  int b = blockIdx.x; int base = b*1024 + threadIdx.x*4; int o = boff[b];
  #pragma unroll
  for (int i=0;i<4;i++) if (base+i < SCN) part[base+i] += o;
}

// ---------------- CSR bucket fill ----------------
__global__ __launch_bounds__(256) void k_fill(
    const int* __restrict__ p_v, const int* __restrict__ p_c,
    const int* __restrict__ n_v, const int* __restrict__ n_c,
    const int* __restrict__ starts, int* __restrict__ fill, int* __restrict__ listBuf)
{
  int i = blockIdx.x*256 + threadIdx.x;
  if (i < EPN){
    int v = p_v[i], c = p_c[i];
    int s1 = starts[v]        + atomicAdd(&fill[v], 1);          listBuf[s1] = c; // PV
    int s2 = starts[2*VN + c] + atomicAdd(&fill[2*VN + c], 1);   listBuf[s2] = v; // PC
  }
  if (i < ENN){
    int v = n_v[i], c = n_c[i];
    int s1 = starts[VN + v]        + atomicAdd(&fill[VN + v], 1);        listBuf[s1] = c; // NV
    int s2 = starts[2*VN + CN + c] + atomicAdd(&fill[2*VN + CN + c], 1); listBuf[s2] = v; // NC
  }
}

__global__ __launch_bounds__(256) void k_rdeg(const int* __restrict__ cnt, float* __restrict__ rdeg){
  int i = blockIdx.x*256 + threadIdx.x;
  if (i < SCN) rdeg[i] = 1.0f / (float)max(cnt[i], 1);
}

// ---------------- weight packing: W[K][N] f32 -> fragment-major bf16 ----------------
__global__ __launch_bounds__(256) void k_pack(const float* __restrict__ W, unsigned short* __restrict__ Wp, int K, int N){
  int o = blockIdx.x*256 + threadIdx.x;
  if (o >= K*N) return;
  int j = o & 7, l = (o>>3) & 63, frag = o >> 9;
  int K32 = K >> 5;
  int n0 = frag / K32, k0 = frag - n0*K32;
  int k = k0*32 + (l>>4)*8 + j, n = n0*16 + (l&15);
  Wp[o] = f2b(W[(size_t)k*N + n]);
}

// ---------------- GRU weight packing: per-(col-tile,gate) contiguous 12KB blocks ----------------
__global__ __launch_bounds__(256) void k_packgru(
    const float* __restrict__ Wih, const float* __restrict__ Whh,
    unsigned short* __restrict__ Wg)
{
  int idx = blockIdx.x*256 + threadIdx.x;
  if (idx >= 8*18432) return;
  int n0l = idx / 18432;
  int r = idx - n0l*18432;
  int g = r / 6144;
  int r2 = r - g*6144;
  int ih = (r2 < 4096) ? 1 : 0;
  int r3 = ih ? r2 : r2 - 4096;
  int k0 = r3 >> 9;
  int e = r3 & 511;
  int l = e >> 3, j = e & 7;
  int k = k0*32 + (l>>4)*8 + j;
  int n = g*128 + n0l*16 + (l&15);
  float v = ih ? Wih[(size_t)k*384 + n] : Whh[(size_t)k*384 + n];
  Wg[idx] = f2b(v);
}

// packed gate biases: b4[c] = { bih[c]+bhh[c], bih[128+c]+bhh[128+c], bih[256+c], bhh[256+c] }
__global__ __launch_bounds__(128) void k_packbias(
    const float* __restrict__ bih, const float* __restrict__ bhh, float4* __restrict__ b4)
{
  int c = threadIdx.x;
  b4[c] = make_float4(bih[c]+bhh[c], bih[DD+c]+bhh[DD+c], bih[2*DD+c], bhh[2*DD+c]);
}

__global__ __launch_bounds__(256) void k_init(const float* __restrict__ ini, unsigned short* __restrict__ emb, int total){
  int i = blockIdx.x*256 + threadIdx.x;
  if (i < total) emb[i] = f2b(ini[i & (DD-1)] * 0.08838834764831845f); // 1/sqrt(128)
}

// ---------------- dual two-layer MLP: 32 rows/wave, 8KB LDS/wave, bf16 X ----------------
__global__ __launch_bounds__(256) void k_mlp2dual(
    const unsigned short* __restrict__ X,
    const unsigned short* __restrict__ W1p, const float* __restrict__ b1p,
    const unsigned short* __restrict__ W2p, const float* __restrict__ b2p,
    const unsigned short* __restrict__ W1n, const float* __restrict__ b1n,
    const unsigned short* __restrict__ W2n, const float* __restrict__ b2n,
    unsigned short* __restrict__ Hp, unsigned short* __restrict__ Hn, int M)
{
  __shared__ __align__(16) char smem[32768];
  int t = threadIdx.x, lane = t & 63, wid = t >> 6;
  int r0 = blockIdx.x*128 + wid*32;
  if (r0 >= M) return;  // per-wave LDS only; no block barriers
  char* sW = smem + wid*8192;   // [32][128] bf16 swizzled; reused X -> H1 -> out
  int row16 = lane & 15, hq = lane >> 4, col0 = row16;

  // stage 32 rows of X (bf16, coalesced uint4) -> swizzled
  #pragma unroll
  for (int q=0;q<8;q++){
    int i = q*64 + lane; int row = i >> 4, cb = i & 15;
    int gr = r0 + row; if (gr >= M) gr = M-1;
    uint4 u = *(const uint4*)&X[(size_t)gr*DD + cb*8];
    *(uint4*)&sW[row*256 + ((cb^(row&7))<<4)] = u;
  }
  bf16x8 aX[2][4];
  #pragma unroll
  for (int tt=0;tt<2;tt++){
    int rowl = tt*16 + row16;
    #pragma unroll
    for (int k0=0;k0<4;k0++)
      aX[tt][k0] = *(const bf16x8*)&sW[rowl*256 + (((k0*4+hq)^(rowl&7))<<4)];
  }
  #pragma unroll
  for (int pn=0; pn<2; pn++){
    const unsigned short* W1 = pn? W1n : W1p; const float* b1 = pn? b1n : b1p;
    const unsigned short* W2 = pn? W2n : W2p; const float* b2 = pn? b2n : b2p;
    unsigned short* Hout = pn? Hn : Hp;
    // ---- layer 1: relu(X@W1+b1) -> sW ----
    bf16x8 wn[4];
    #pragma unroll
    for (int k0=0;k0<4;k0++) wn[k0] = *(const bf16x8*)&W1[((size_t)k0*64+lane)*8];
    #pragma unroll
    for (int n0=0;n0<8;n0++){
      bf16x8 wc[4];
      #pragma unroll
      for (int k0=0;k0<4;k0++) wc[k0] = wn[k0];
      if (n0 < 7){
        #pragma unroll
        for (int k0=0;k0<4;k0++) wn[k0] = *(const bf16x8*)&W1[((size_t)((n0+1)*4+k0)*64+lane)*8];
      }
      f32x4 acc[2] = {{0,0,0,0},{0,0,0,0}};
      #pragma unroll
      for (int k0=0;k0<4;k0++)
        #pragma unroll
        for (int tt=0;tt<2;tt++)
          acc[tt] = __builtin_amdgcn_mfma_f32_16x16x32_bf16(aX[tt][k0], wc[k0], acc[tt], 0,0,0);
      int col = n0*16 + col0;
      float bb = b1[col];
      #pragma unroll
      for (int tt=0;tt<2;tt++)
        #pragma unroll
        for (int r=0;r<4;r++){
          float v = fmaxf(acc[tt][r]+bb, 0.f);
          int rowl = tt*16 + hq*4 + r;
          *(unsigned short*)&sW[rowl*256 + (((col>>3)^(rowl&7))<<4) + (col&7)*2] = f2b(v);
        }
    }
    // ---- layer 2: H@W2+b2 ----
    bf16x8 aH[2][4];
    #pragma unroll
    for (int tt=0;tt<2;tt++){
      int rowl = tt*16 + row16;
      #pragma unroll
      for (int k0=0;k0<4;k0++)
        aH[tt][k0] = *(const bf16x8*)&sW[rowl*256 + (((k0*4+hq)^(rowl&7))<<4)];
    }
    #pragma unroll
    for (int k0=0;k0<4;k0++) wn[k0] = *(const bf16x8*)&W2[((size_t)k0*64+lane)*8];
    #pragma unroll
    for (int n0=0;n0<8;n0++){
      bf16x8 wc[4];
      #pragma unroll
      for (int k0=0;k0<4;k0++) wc[k0] = wn[k0];
      if (n0 < 7){
        #pragma unroll
        for (int k0=0;k0<4;k0++) wn[k0] = *(const bf16x8*)&W2[((size_t)((n0+1)*4+k0)*64+lane)*8];
      }
      f32x4 acc[2] = {{0,0,0,0},{0,0,0,0}};
      #pragma unroll
      for (int k0=0;k0<4;k0++)
        #pragma unroll
        for (int tt=0;tt<2;tt++)
          acc[tt] = __builtin_amdgcn_mfma_f32_16x16x32_bf16(aH[tt][k0], wc[k0], acc[tt], 0,0,0);
      int col = n0*16 + col0;
      float bb = b2[col];
      #pragma unroll
      for (int tt=0;tt<2;tt++)
        #pragma unroll
        for (int r=0;r<4;r++){
          int rowl = tt*16 + hq*4 + r;
          *(unsigned short*)&sW[rowl*256 + (((col>>3)^(rowl&7))<<4) + (col&7)*2] = f2b(acc[tt][r]+bb);
        }
    }
    // cooperative (within-wave) coalesced store of 32 rows
    #pragma unroll
    for (int q=0;q<8;q++){
      int i = lane + q*64; int rowl = i>>4, cb = i&15;
      int grow = r0 + rowl;
      if (grow < M)
        *(uint4*)&Hout[(size_t)grow*DD + cb*8] = *(const uint4*)&sW[rowl*256 + ((cb^(rowl&7))<<4)];
    }
  }
}

// ---------------- CSR gather-mean aggregation: 16 lanes/dest, interleaved p/n chains ----------------
__global__ __launch_bounds__(256) void k_aggr(
    const unsigned short* __restrict__ Hp, const unsigned short* __restrict__ Hn,
    const int* __restrict__ starts, const float* __restrict__ rdeg, const int* __restrict__ listBuf,
    unsigned short* __restrict__ Xg, int baseP, int baseN, int M)
{
  int d = blockIdx.x*16 + (threadIdx.x >> 4);
  if (d >= M) return;
  int l16 = threadIdx.x & 15;
  int qp = starts[baseP + d], ep = starts[baseP + d + 1];
  int qn = starts[baseN + d], en = starts[baseN + d + 1];
  float ap[8], an[8];
  #pragma unroll
  for (int j=0;j<8;j++){ ap[j]=0.f; an[j]=0.f; }
  while (qp < ep && qn < en){
    int sp_ = listBuf[qp++];
    int sn_ = listBuf[qn++];
    uint4 up = *(const uint4*)&Hp[(size_t)sp_*DD + l16*8];
    uint4 un = *(const uint4*)&Hn[(size_t)sn_*DD + l16*8];
    ap[0]+=b2f((unsigned short)up.x); ap[1]+=b2f((unsigned short)(up.x>>16));
    ap[2]+=b2f((unsigned short)up.y); ap[3]+=b2f((unsigned short)(up.y>>16));
    ap[4]+=b2f((unsigned short)up.z); ap[5]+=b2f((unsigned short)(up.z>>16));
    ap[6]+=b2f((unsigned short)up.w); ap[7]+=b2f((unsigned short)(up.w>>16));
    an[0]+=b2f((unsigned short)un.x); an[1]+=b2f((unsigned short)(un.x>>16));
    an[2]+=b2f((unsigned short)un.y); an[3]+=b2f((unsigned short)(un.y>>16));
    an[4]+=b2f((unsigned short)un.z); an[5]+=b2f((unsigned short)(un.z>>16));
    an[6]+=b2f((unsigned short)un.w); an[7]+=b2f((unsigned short)(un.w>>16));
  }
  while (qp < ep){
    int src = listBuf[qp++];
    uint4 u = *(const uint4*)&Hp[(size_t)src*DD + l16*8];
    ap[0]+=b2f((unsigned short)u.x); ap[1]+=b2f((unsigned short)(u.x>>16));
    ap[2]+=b2f((unsigned short)u.y); ap[3]+=b2f((unsigned short)(u.y>>16));
    ap[4]+=b2f((unsigned short)u.z); ap[5]+=b2f((unsigned short)(u.z>>16));
    ap[6]+=b2f((unsigned short)u.w); ap[7]+=b2f((unsigned short)(u.w>>16));
  }
  while (qn < en){
    int src = listBuf[qn++];
    uint4 u = *(const uint4*)&Hn[(size_t)src*DD + l16*8];
    an[0]+=b2f((unsigned short)u.x); an[1]+=b2f((unsigned short)(u.x>>16));
    an[2]+=b2f((unsigned short)u.y); an[3]+=b2f((unsigned short)(u.y>>16));
    an[4]+=b2f((unsigned short)u.z); an[5]+=b2f((unsigned short)(u.z>>16));
    an[6]+=b2f((unsigned short)u.w); an[7]+=b2f((unsigned short)(u.w>>16));
  }
  float rp = rdeg[baseP + d];
  float rn = rdeg[baseN + d];
  uint4 o;
  o.x = (unsigned)f2b(ap[0]*rp) | ((unsigned)f2b(ap[1]*rp)<<16);
  o.y = (unsigned)f2b(ap[2]*rp) | ((unsigned)f2b(ap[3]*rp)<<16);
  o.z = (unsigned)f2b(ap[4]*rp) | ((unsigned)f2b(ap[5]*rp)<<16);
  o.w = (unsigned)f2b(ap[6]*rp) | ((unsigned)f2b(ap[7]*rp)<<16);
  *(uint4*)&Xg[(size_t)d*(2*DD) + l16*8] = o;
  o.x = (unsigned)f2b(an[0]*rn) | ((unsigned)f2b(an[1]*rn)<<16);
  o.y = (unsigned)f2b(an[2]*rn) | ((unsigned)f2b(an[3]*rn)<<16);
  o.z = (unsigned)f2b(an[4]*rn) | ((unsigned)f2b(an[5]*rn)<<16);
  o.w = (unsigned)f2b(an[6]*rn) | ((unsigned)f2b(an[7]*rn)<<16);
  *(uint4*)&Xg[(size_t)d*(2*DD) + DD + l16*8] = o;
}

// ---------------- fused GRU: 8-wave shared staging, reg-staged pipeline, bf16 h ----------------
// 8 waves x 32 rows = 256 rows/block. 24 sub-phases, 12KB weights each, shared by all
// 8 waves (half the staging traffic of the 4-wave version). Thread t stages slot t
// (16B) and, for t<256, slot 512+t (wave-uniform branch).
__global__ __launch_bounds__(512) void k_gru(
    const unsigned short* __restrict__ hR, unsigned short* __restrict__ hW,
    const unsigned short* __restrict__ Xg,
    const unsigned short* __restrict__ Wg,
    const float4* __restrict__ b4,
    int M)
{
  __shared__ __align__(16) char sW[2][12288];
  int t = threadIdx.x, lane = t & 63;
  int wid = t >> 6;
  int r0 = blockIdx.x*256 + wid*32;
  int row16 = lane & 15, hq = lane >> 4, col0 = row16;
  int kb = hq*8;
  // A fragments (rows clamped; no early return — barriers below)
  bf16x8 aX[2][8];
  bf16x8 aH[2][4];
  #pragma unroll
  for (int tt=0;tt<2;tt++){
    int row = r0 + tt*16 + row16; if (row >= M) row = M-1;
    const unsigned short* xp = &Xg[(size_t)row*(2*DD) + kb];
    #pragma unroll
    for (int k0=0;k0<8;k0++) aX[tt][k0] = *(const bf16x8*)(xp + k0*32);
    const unsigned short* hp = &hR[(size_t)row*DD + kb];
    #pragma unroll
    for (int k0=0;k0<4;k0++) aH[tt][k0] = *(const bf16x8*)(hp + k0*32);
  }
  // staging: thread t owns slot t (first 8KB); t<256 additionally owns slot 512+t (last 4KB)
  const char* wsrc0 = (const char*)Wg + (size_t)t*16;
  const char* wsrc1 = (const char*)Wg + 8192 + (size_t)t*16;
  char* d00 = &sW[0][(size_t)t*16];
  char* d01 = &sW[0][8192 + (size_t)t*16];
  char* d10 = &sW[1][(size_t)t*16];
  char* d11 = &sW[1][8192 + (size_t)t*16];
  bool xtra = (t < 256);
  uint4 wr0 = *(const uint4*)(wsrc0);
  uint4 wr1 = xtra ? *(const uint4*)(wsrc1) : wr0;
  f32x4 rr0, rr1, zz0, zz1, hp0, hp1, bb;
  #pragma unroll 1
  for (int sp = 0; sp < 24; sp++){
    int cur = sp & 1;
    // publish this sub-phase's weights (loaded last iteration / prologue)
    if (!cur){
      *(uint4*)(d00) = wr0;
      if (xtra) *(uint4*)(d01) = wr1;
    } else {
      *(uint4*)(d10) = wr0;
      if (xtra) *(uint4*)(d11) = wr1;
    }
    __syncthreads();
    // issue next sub-phase's loads AFTER the barrier: full compute phase of slack
    if (sp < 23){
      size_t o = (size_t)(sp+1)*12288;
      wr0 = *(const uint4*)(wsrc0 + o);
      if (xtra) wr1 = *(const uint4*)(wsrc1 + o);
    }
    int n0l = sp / 3;
    int gate = sp - n0l*3;
    int col = n0l*16 + col0;
    const char* wb = &sW[cur][0] + lane*16;
    // X-part and H-part accumulated separately (N gate needs them split)
    f32x4 xa0 = {0,0,0,0}, xa1 = {0,0,0,0};
    f32x4 ha0 = {0,0,0,0}, ha1 = {0,0,0,0};
    #pragma unroll
    for (int k0=0;k0<8;k0++){
      bf16x8 w = *(const bf16x8*)(wb + k0*1024);
      xa0 = __builtin_amdgcn_mfma_f32_16x16x32_bf16(aX[0][k0], w, xa0, 0,0,0);
      xa1 = __builtin_amdgcn_mfma_f32_16x16x32_bf16(aX[1][k0], w, xa1, 0,0,0);
    }
    #pragma unroll
    for (int k0=0;k0<4;k0++){
      bf16x8 w = *(const bf16x8*)(wb + 8192 + k0*1024);
      ha0 = __builtin_amdgcn_mfma_f32_16x16x32_bf16(aH[0][k0], w, ha0, 0,0,0);
      ha1 = __builtin_amdgcn_mfma_f32_16x16x32_bf16(aH[1][k0], w, ha1, 0,0,0);
    }
    if (gate == 0){
      float4 b = b4[col];
      bb[0]=b.x; bb[1]=b.y; bb[2]=b.z; bb[3]=b.w;
      #pragma unroll
      for (int r=0;r<4;r++){
        rr0[r] = sigm(xa0[r] + ha0[r] + bb[0]);
        rr1[r] = sigm(xa1[r] + ha1[r] + bb[0]);
      }
      // prefetch old-h epilogue values (ready 2 sub-phases later at the N gate)
      #pragma unroll
      for (int r=0;r<4;r++){
        int g0 = r0 + hq*4 + r;      if (g0 >= M) g0 = M-1;
        int g1 = r0 + 16 + hq*4 + r; if (g1 >= M) g1 = M-1;
        hp0[r] = b2f(hR[(size_t)g0*DD + col]);
        hp1[r] = b2f(hR[(size_t)g1*DD + col]);
      }
    } else if (gate == 1){
      #pragma unroll
      for (int r=0;r<4;r++){
        zz0[r] = sigm(xa0[r] + ha0[r] + bb[1]);
        zz1[r] = sigm(xa1[r] + ha1[r] + bb[1]);
      }
    } else {
      #pragma unroll
      for (int r=0;r<4;r++){
        int g0 = r0 + hq*4 + r;
        if (g0 < M){
          float nn = ftanh(xa0[r] + bb[2] + rr0[r]*(ha0[r] + bb[3]));
          hW[(size_t)g0*DD + col] = f2b((1.f - zz0[r])*nn + zz0[r]*hp0[r]);
        }
        int g1 = r0 + 16 + hq*4 + r;
        if (g1 < M){
          float nn = ftanh(xa1[r] + bb[2] + rr1[r]*(ha1[r] + bb[3]));
          hW[(size_t)g1*DD + col] = f2b((1.f - zz1[r])*nn + zz1[r]*hp1[r]);
        }
      }
    }
    // no trailing barrier needed: next ds_write targets the OTHER buffer,
    // whose last readers finished before the barrier above.
  }
}

// ---------------- per-graph mean readout ----------------
__global__ __launch_bounds__(256) void k_batchsum(
    const unsigned short* __restrict__ v_emb, const int* __restrict__ vb,
    float* __restrict__ g_sum, float* __restrict__ g_cnt)
{
  int c = threadIdx.x & (DD-1);
  int half = threadIdx.x >> 7;
  int rs = blockIdx.x*128 + half*64;
  if (rs >= VN) return;
  int re = rs + 64; if (re > VN) re = VN;
  float acc = 0.f, cnt = 0.f;
  int cur = vb[rs];
  for (int r = rs; r < re; r++){
    int b = vb[r];
    if (b != cur){
      atomicAdd(&g_sum[cur*DD + c], acc);
      if (c == 0) atomicAdd(&g_cnt[cur], cnt);
      acc = 0.f; cnt = 0.f; cur = b;
    }
    acc += b2f(v_emb[(size_t)r*DD + c]);
    cnt += 1.f;
  }
  atomicAdd(&g_sum[cur*DD + c], acc);
  if (c == 0) atomicAdd(&g_cnt[cur], cnt);
}

__global__ __launch_bounds__(128) void k_readout(
    const float* __restrict__ g_sum, const float* __restrict__ g_cnt,
    const float* __restrict__ W1, const float* __restrict__ b1,
    const float* __restrict__ W2, const float* __restrict__ b2,
    float* __restrict__ out)
{
  __shared__ float sg[DD];
  __shared__ float sr[DD];
  int b = blockIdx.x, c = threadIdx.x;
  float rc = 1.0f / fmaxf(g_cnt[b], 1.0f);
  sg[c] = g_sum[b*DD + c] * rc;
  __syncthreads();
  float a = b1[c];
  for (int k=0;k<DD;k++) a = fmaf(sg[k], W1[(size_t)k*DD + c], a);
  a = fmaxf(a, 0.f);
  sr[c] = a * W2[c];
  __syncthreads();
  for (int s=64; s>0; s>>=1){
    if (c < s) sr[c] += sr[c+s];
    __syncthreads();
  }
  if (c == 0) out[b] = sigm(sr[0] + b2[0]);
}

// ---------------- orchestration ----------------
extern "C" void kernel_launch(void* const* d_in, const int* in_sizes, int n_in,
                              void* d_out, int out_size, void* d_ws, size_t ws_size,
                              hipStream_t stream)
{
  const int* vE = (const int*)d_in[0];
  const int* cE = (const int*)d_in[1];
  const int* pE = (const int*)d_in[2];
  const int* nE = (const int*)d_in[3];
  const int* vb = (const int*)d_in[4];
  const float* v_init = (const float*)d_in[5];
  const float* c_init = (const float*)d_in[6];
  const float* mW1[4]; const float* mb1[4]; const float* mW2[4]; const float* mb2[4];
  for (int m=0;m<4;m++){
    mW1[m] = (const float*)d_in[7 + m*4 + 0];
    mb1[m] = (const float*)d_in[7 + m*4 + 1];
    mW2[m] = (const float*)d_in[7 + m*4 + 2];
    mb2[m] = (const float*)d_in[7 + m*4 + 3];
  }
  const float* gc_Wih = (const float*)d_in[23];
  const float* gc_Whh = (const float*)d_in[24];
  const float* gc_bih = (const float*)d_in[25];
  const float* gc_bhh = (const float*)d_in[26];
  const float* gv_Wih = (const float*)d_in[27];
  const float* gv_Whh = (const float*)d_in[28];
  const float* gv_bih = (const float*)d_in[29];
  const float* gv_bhh = (const float*)d_in[30];
  const float* ro_W1 = (const float*)d_in[31];
  const float* ro_b1 = (const float*)d_in[32];
  const float* ro_W2 = (const float*)d_in[33];
  const float* ro_b2 = (const float*)d_in[34];
  float* out = (float*)d_out;

  char* base = (char*)d_ws;
  size_t off = 0;
  auto alloc = [&](size_t n)->void*{ void* p = base + off; off += (n + 255) & ~(size_t)255; return p; };
  int* cnt4    = (int*)alloc((size_t)SCN*4);
  int* fill4   = (int*)alloc((size_t)SCN*4);
  int* starts  = (int*)alloc(((size_t)SCN+1)*4);
  int* bsum    = (int*)alloc(512*4);
  int* boff    = (int*)alloc(512*4);
  int* p_v     = (int*)alloc((size_t)EPN*4);
  int* p_c     = (int*)alloc((size_t)EPN*4);
  int* n_v     = (int*)alloc((size_t)ENN*4);
  int* n_c     = (int*)alloc((size_t)ENN*4);
  int* listBuf = (int*)alloc((size_t)2*(EPN+ENN)*4);
  float* rdeg4 = (float*)alloc((size_t)SCN*4);
  unsigned short* v_embA = (unsigned short*)alloc((size_t)VN*DD*2);
  unsigned short* v_embB = (unsigned short*)alloc((size_t)VN*DD*2);
  unsigned short* c_embA = (unsigned short*)alloc((size_t)CN*DD*2);
  unsigned short* c_embB = (unsigned short*)alloc((size_t)CN*DD*2);
  unsigned short* Hp = (unsigned short*)alloc((size_t)CN*DD*2);
  unsigned short* Hn = (unsigned short*)alloc((size_t)CN*DD*2);
  unsigned short* Xg = (unsigned short*)alloc((size_t)CN*2*DD*2);
  unsigned short* P_W1[4]; unsigned short* P_W2[4];
  for (int m=0;m<4;m++){
    P_W1[m] = (unsigned short*)alloc((size_t)DD*DD*2);
    P_W2[m] = (unsigned short*)alloc((size_t)DD*DD*2);
  }
  unsigned short* P_gc = (unsigned short*)alloc((size_t)8*18432*2);
  unsigned short* P_gv = (unsigned short*)alloc((size_t)8*18432*2);
  float4* P_bc = (float4*)alloc((size_t)DD*16);
  float4* P_bv = (float4*)alloc((size_t)DD*16);
  float* g_sum = (float*)alloc((size_t)BN*DD*4);
  float* g_cnt = (float*)alloc((size_t)BN*4);
  (void)in_sizes; (void)n_in; (void)out_size; (void)ws_size;

  hipMemsetAsync(cnt4, 0, (size_t)SCN*4, stream);
  hipMemsetAsync(fill4, 0, (size_t)SCN*4, stream);

  k_edges<<<(EPN+255)/256, 256, 0, stream>>>(vE, cE, pE, nE, p_v, p_c, n_v, n_c, cnt4);
  k_scan1<<<SC_NB, 256, 0, stream>>>(cnt4, starts, bsum);
  k_scan2<<<1, 512, 0, stream>>>(bsum, boff, starts + SCN);
  k_scan3<<<SC_NB, 256, 0, stream>>>(starts, boff);
  k_fill<<<(EPN+255)/256, 256, 0, stream>>>(p_v, p_c, n_v, n_c, starts, fill4, listBuf);
  k_rdeg<<<(SCN+255)/256, 256, 0, stream>>>(cnt4, rdeg4);

  for (int m=0;m<4;m++){
    k_pack<<<(DD*DD+255)/256, 256, 0, stream>>>(mW1[m], P_W1[m], DD, DD);
    k_pack<<<(DD*DD+255)/256, 256, 0, stream>>>(mW2[m], P_W2[m], DD, DD);
  }
  k_packgru<<<(8*18432+255)/256, 256, 0, stream>>>(gc_Wih, gc_Whh, P_gc);
  k_packgru<<<(8*18432+255)/256, 256, 0, stream>>>(gv_Wih, gv_Whh, P_gv);
  k_packbias<<<1, 128, 0, stream>>>(gc_bih, gc_bhh, P_bc);
  k_packbias<<<1, 128, 0, stream>>>(gv_bih, gv_bhh, P_bv);

  k_init<<<((size_t)VN*DD+255)/256, 256, 0, stream>>>(v_init, v_embA, VN*DD);
  k_init<<<((size_t)CN*DD+255)/256, 256, 0, stream>>>(c_init, c_embA, CN*DD);

  int mlpVb = (VN+127)/128, mlpCb = (CN+127)/128;
  int gruVb = (VN+255)/256, gruCb = (CN+255)/256;
  unsigned short* vc = v_embA; unsigned short* va = v_embB;
  unsigned short* cc = c_embA; unsigned short* ca = c_embB;
  for (int it=0; it<3; ++it){
    // ---- v -> c ----
    k_mlp2dual<<<mlpVb, 256, 0, stream>>>(vc, P_W1[0], mb1[0], P_W2[0], mb2[0],
                                                   P_W1[1], mb1[1], P_W2[1], mb2[1], Hp, Hn, VN);
    k_aggr<<<(CN+15)/16, 256, 0, stream>>>(Hp, Hn, starts, rdeg4, listBuf, Xg, 2*VN, 2*VN+CN, CN);
    k_gru<<<gruCb, 512, 0, stream>>>(cc, ca, Xg, P_gc, P_bc, CN);
    { unsigned short* tmp = cc; cc = ca; ca = tmp; }
    // ---- c -> v ----
    k_mlp2dual<<<mlpCb, 256, 0, stream>>>(cc, P_W1[2], mb1[2], P_W2[2], mb2[2],
                                                   P_W1[3], mb1[3], P_W2[3], mb2[3], Hp, Hn, CN);
    k_aggr<<<(VN+15)/16, 256, 0, stream>>>(Hp, Hn, starts, rdeg4, listBuf, Xg, 0, VN, VN);
    k_gru<<<gruVb, 512, 0, stream>>>(vc, va, Xg, P_gv, P_bv, VN);
    { unsigned short* tmp = vc; vc = va; va = tmp; }
  }

  hipMemsetAsync(g_sum, 0, (size_t)BN*DD*4, stream);
  hipMemsetAsync(g_cnt, 0, (size_t)BN*4, stream);
  k_batchsum<<<(VN+127)/128, 256, 0, stream>>>(vc, vb, g_sum, g_cnt);
  k_readout<<<BN, 128, 0, stream>>>(g_sum, g_cnt, ro_W1, ro_b1, ro_W2, ro_b2, out);
}